// Round 12
// baseline (349.321 us; speedup 1.0000x reference)
//
#include <hip/hip_runtime.h>

#define N_NODES 50000
#define N_EDGES 800000
#define D_IN 16
#define HID 128
#define D_OUT 4
#define N_LAYERS 3
#define LN_EPS 1e-5f
#define ELL_CAP 48
#define CURS 16                               // cursor stride (ints)
#define NB_FILL ((N_EDGES + 255) / 256)       // 3125
#define NB_W    (N_LAYERS * 128)              // 384
#define NB_IN   ((N_NODES + 3) / 4)           // 12500

typedef __attribute__((ext_vector_type(8))) short bf16x8;
typedef __attribute__((ext_vector_type(4))) float f32x4;

__device__ __forceinline__ unsigned short f2bf(float f) {
    union { float f; unsigned int u; } a; a.f = f;
    unsigned int r = a.u + 0x7fffu + ((a.u >> 16) & 1u);   // RNE
    return (unsigned short)(r >> 16);
}
__device__ __forceinline__ unsigned int pack2(float x, float y) {
    return (unsigned int)f2bf(x) | ((unsigned int)f2bf(y) << 16);
}
__device__ __forceinline__ float bf_lo(unsigned int u) {
    union { unsigned int u; float f; } c; c.u = u << 16; return c.f;
}
__device__ __forceinline__ float bf_hi(unsigned int u) {
    union { unsigned int u; float f; } c; c.u = u & 0xffff0000u; return c.f;
}

// ---- ELL fill, TRANSPOSED layout: ell_t[slot][node] (writes stay L2-resident) ----
__global__ __launch_bounds__(256) void fill_kernel(
        const int* __restrict__ src, const int* __restrict__ dst,
        int* __restrict__ cursor, int* __restrict__ ell_t) {
    int e = blockIdx.x * 256 + threadIdx.x;
    if (e >= N_EDGES) return;
    int d = dst[e];
    int slot = atomicAdd(&cursor[(size_t)d * CURS], 1);
    if (slot < ELL_CAP) ell_t[(size_t)slot * N_NODES + d] = src[e];
}

// ---- winp: weight transpose + in_proj/first-LN (unchanged code, own dispatch) ----
__global__ __launch_bounds__(256) void winp_kernel(
        const float* __restrict__ Wl, const float* __restrict__ Wr,
        unsigned short* __restrict__ BT,
        const float* __restrict__ x, const float* __restrict__ W_in,
        const float* __restrict__ b_in,
        const float* __restrict__ g0, const float* __restrict__ bb0,
        float* __restrict__ h, unsigned short* __restrict__ ahn) {
    int b = blockIdx.x, t = threadIdx.x;
    if (b < NB_W) {                           // BT[i][n][k]
        int i = b >> 7, n = b & 127;
        float v = (t < 128) ? Wl[((size_t)i * 128 + t) * 128 + n]
                            : Wr[((size_t)i * 128 + (t - 128)) * 128 + n];
        BT[((size_t)i * 128 + n) * 256 + t] = f2bf(v);
        return;
    }
    b -= NB_W;                                // in_proj + first LN
    int wave = t >> 6, lane = t & 63;
    int node = b * 4 + wave;
    if (node >= N_NODES) return;
    int j0 = lane * 2;
    float a0 = b_in[j0], a1 = b_in[j0 + 1];
    const float* xr = x + (size_t)node * D_IN;
    #pragma unroll
    for (int k = 0; k < D_IN; ++k) {
        float xv = xr[k];
        float2 w = *(const float2*)(W_in + k * HID + j0);
        a0 += xv * w.x;
        a1 += xv * w.y;
    }
    float2 hv; hv.x = a0; hv.y = a1;
    *(float2*)(h + (size_t)node * HID + j0) = hv;
    float s = a0 + a1;
    #pragma unroll
    for (int o = 32; o > 0; o >>= 1) s += __shfl_xor(s, o, 64);
    float mu = s * (1.0f / HID);
    float d0 = a0 - mu, d1 = a1 - mu;
    float q = d0 * d0 + d1 * d1;
    #pragma unroll
    for (int o = 32; o > 0; o >>= 1) q += __shfl_xor(q, o, 64);
    float rstd = rsqrtf(q * (1.0f / HID) + LN_EPS);
    float2 gg = *(const float2*)(g0 + j0);
    float2 bb = *(const float2*)(bb0 + j0);
    ((unsigned int*)(ahn + (size_t)node * 256))[64 + lane] =
        pack2(d0 * rstd * gg.x + bb.x, d1 * rstd * gg.y + bb.y);
}

// ---- agg half of ahn[n] = bf16( mean hn_bf16[src] ) from transposed ELL
//      quarter-wave per node, uint4 loads, up to 8 edges in flight ----
__global__ __launch_bounds__(256) void gather_kernel(
        const int* __restrict__ cursor, const int* __restrict__ ell_t,
        unsigned short* __restrict__ ahn) {
    int tid = threadIdx.x;
    int node = blockIdx.x * 16 + (tid >> 4);
    if (node >= N_NODES) return;
    int l = tid & 15;
    int qbase = (tid & 63) & ~15;
    const uint4* base = (const uint4*)ahn;      // row = 32 uint4; hn half at +16
    int cnt = cursor[(size_t)node * CURS];
    int m = cnt < ELL_CAP ? cnt : ELL_CAP;
    float a0 = 0.f, a1 = 0.f, a2 = 0.f, a3 = 0.f, a4 = 0.f, a5 = 0.f, a6 = 0.f, a7 = 0.f;
    int i = 0;
    for (; i + 8 <= m; i += 8) {
        int sv = ell_t[(size_t)(i + (l & 7)) * N_NODES + node];  // lane qbase+j: slot i+(j&7)
        int s0 = __shfl(sv, qbase + 0, 64);
        int s1 = __shfl(sv, qbase + 1, 64);
        int s2 = __shfl(sv, qbase + 2, 64);
        int s3 = __shfl(sv, qbase + 3, 64);
        int s4 = __shfl(sv, qbase + 4, 64);
        int s5 = __shfl(sv, qbase + 5, 64);
        int s6 = __shfl(sv, qbase + 6, 64);
        int s7 = __shfl(sv, qbase + 7, 64);
        uint4 v0 = base[(size_t)s0 * 32 + 16 + l];
        uint4 v1 = base[(size_t)s1 * 32 + 16 + l];
        uint4 v2 = base[(size_t)s2 * 32 + 16 + l];
        uint4 v3 = base[(size_t)s3 * 32 + 16 + l];
        uint4 v4 = base[(size_t)s4 * 32 + 16 + l];
        uint4 v5 = base[(size_t)s5 * 32 + 16 + l];
        uint4 v6 = base[(size_t)s6 * 32 + 16 + l];
        uint4 v7 = base[(size_t)s7 * 32 + 16 + l];
        a0 += ((bf_lo(v0.x) + bf_lo(v1.x)) + (bf_lo(v2.x) + bf_lo(v3.x)))
            + ((bf_lo(v4.x) + bf_lo(v5.x)) + (bf_lo(v6.x) + bf_lo(v7.x)));
        a1 += ((bf_hi(v0.x) + bf_hi(v1.x)) + (bf_hi(v2.x) + bf_hi(v3.x)))
            + ((bf_hi(v4.x) + bf_hi(v5.x)) + (bf_hi(v6.x) + bf_hi(v7.x)));
        a2 += ((bf_lo(v0.y) + bf_lo(v1.y)) + (bf_lo(v2.y) + bf_lo(v3.y)))
            + ((bf_lo(v4.y) + bf_lo(v5.y)) + (bf_lo(v6.y) + bf_lo(v7.y)));
        a3 += ((bf_hi(v0.y) + bf_hi(v1.y)) + (bf_hi(v2.y) + bf_hi(v3.y)))
            + ((bf_hi(v4.y) + bf_hi(v5.y)) + (bf_hi(v6.y) + bf_hi(v7.y)));
        a4 += ((bf_lo(v0.z) + bf_lo(v1.z)) + (bf_lo(v2.z) + bf_lo(v3.z)))
            + ((bf_lo(v4.z) + bf_lo(v5.z)) + (bf_lo(v6.z) + bf_lo(v7.z)));
        a5 += ((bf_hi(v0.z) + bf_hi(v1.z)) + (bf_hi(v2.z) + bf_hi(v3.z)))
            + ((bf_hi(v4.z) + bf_hi(v5.z)) + (bf_hi(v6.z) + bf_hi(v7.z)));
        a6 += ((bf_lo(v0.w) + bf_lo(v1.w)) + (bf_lo(v2.w) + bf_lo(v3.w)))
            + ((bf_lo(v4.w) + bf_lo(v5.w)) + (bf_lo(v6.w) + bf_lo(v7.w)));
        a7 += ((bf_hi(v0.w) + bf_hi(v1.w)) + (bf_hi(v2.w) + bf_hi(v3.w)))
            + ((bf_hi(v4.w) + bf_hi(v5.w)) + (bf_hi(v6.w) + bf_hi(v7.w)));
    }
    for (; i + 4 <= m; i += 4) {
        int sv = ell_t[(size_t)(i + (l & 3)) * N_NODES + node];
        int s0 = __shfl(sv, qbase + 0, 64);
        int s1 = __shfl(sv, qbase + 1, 64);
        int s2 = __shfl(sv, qbase + 2, 64);
        int s3 = __shfl(sv, qbase + 3, 64);
        uint4 v0 = base[(size_t)s0 * 32 + 16 + l];
        uint4 v1 = base[(size_t)s1 * 32 + 16 + l];
        uint4 v2 = base[(size_t)s2 * 32 + 16 + l];
        uint4 v3 = base[(size_t)s3 * 32 + 16 + l];
        a0 += (bf_lo(v0.x) + bf_lo(v1.x)) + (bf_lo(v2.x) + bf_lo(v3.x));
        a1 += (bf_hi(v0.x) + bf_hi(v1.x)) + (bf_hi(v2.x) + bf_hi(v3.x));
        a2 += (bf_lo(v0.y) + bf_lo(v1.y)) + (bf_lo(v2.y) + bf_lo(v3.y));
        a3 += (bf_hi(v0.y) + bf_hi(v1.y)) + (bf_hi(v2.y) + bf_hi(v3.y));
        a4 += (bf_lo(v0.z) + bf_lo(v1.z)) + (bf_lo(v2.z) + bf_lo(v3.z));
        a5 += (bf_hi(v0.z) + bf_hi(v1.z)) + (bf_hi(v2.z) + bf_hi(v3.z));
        a6 += (bf_lo(v0.w) + bf_lo(v1.w)) + (bf_lo(v2.w) + bf_lo(v3.w));
        a7 += (bf_hi(v0.w) + bf_hi(v1.w)) + (bf_hi(v2.w) + bf_hi(v3.w));
    }
    for (; i < m; ++i) {
        int s = ell_t[(size_t)i * N_NODES + node];
        uint4 v = base[(size_t)s * 32 + 16 + l];
        a0 += bf_lo(v.x); a1 += bf_hi(v.x);
        a2 += bf_lo(v.y); a3 += bf_hi(v.y);
        a4 += bf_lo(v.z); a5 += bf_hi(v.z);
        a6 += bf_lo(v.w); a7 += bf_hi(v.w);
    }
    float inv = 1.0f / fmaxf((float)cnt, 1.0f);
    uint4 o;
    o.x = pack2(a0 * inv, a1 * inv);
    o.y = pack2(a2 * inv, a3 * inv);
    o.z = pack2(a4 * inv, a5 * inv);
    o.w = pack2(a6 * inv, a7 * inv);
    ((uint4*)ahn)[(size_t)node * 32 + l] = o;   // agg half
}

// ---- conv: D = ahn(128x256 bf16) @ BT^T; relu(hres + D + bl);
//      mode 1: write h + next-layer LN -> ahn hn-half
//      mode 2: fused out-projection (no h write) ----
__global__ __launch_bounds__(256) void conv_mfma_kernel(
        const float* __restrict__ hres, unsigned short* __restrict__ ahn,
        const unsigned short* __restrict__ BT, const float* __restrict__ bl,
        const float* __restrict__ lng, const float* __restrict__ lnb,
        float* __restrict__ h,
        const float* __restrict__ Wout, const float* __restrict__ bout,
        float* __restrict__ out, int mode) {
    __shared__ unsigned short s_a[128 * 64];   // 16 KB, XOR-swizzled 16B groups
    __shared__ unsigned short s_b[128 * 64];   // 16 KB
    __shared__ float s_bl[128], s_g[128], s_bb[128];
    __shared__ float s_wo[512];
    __shared__ float s_bo[4];
    int tid = threadIdx.x;
    int n0 = blockIdx.x * 128;
    if (tid < 128) {
        s_bl[tid] = bl[tid];
        s_g[tid]  = (mode == 1) ? lng[tid] : 0.f;
        s_bb[tid] = (mode == 1) ? lnb[tid] : 0.f;
    }
    if (mode == 2) {
        s_wo[tid]       = Wout[tid];
        s_wo[tid + 256] = Wout[tid + 256];
        if (tid < 4) s_bo[tid] = bout[tid];
    }
    int w = tid >> 6, lane = tid & 63;
    int q = lane >> 4, c0 = lane & 15;

    f32x4 acc[2][8];
    #pragma unroll
    for (int rt = 0; rt < 2; ++rt)
        #pragma unroll
        for (int ct = 0; ct < 8; ++ct) acc[rt][ct] = (f32x4){0.f, 0.f, 0.f, 0.f};

    for (int kc = 0; kc < 4; ++kc) {
        if (kc) __syncthreads();
        #pragma unroll
        for (int p = 0; p < 4; ++p) {      // stage A chunk
            int f = p * 256 + tid;
            int row = f >> 3, g = f & 7;
            int pos = g ^ (row & 7);
            uint4 v = {0u, 0u, 0u, 0u};
            int node = n0 + row;
            if (node < N_NODES)
                v = *(const uint4*)(ahn + (size_t)node * 256 + kc * 64 + g * 8);
            *(uint4*)(s_a + row * 64 + pos * 8) = v;
        }
        #pragma unroll
        for (int p = 0; p < 4; ++p) {      // stage B chunk
            int f = p * 256 + tid;
            int row = f >> 3, g = f & 7;
            int pos = g ^ (row & 7);
            uint4 v = *(const uint4*)(BT + (size_t)row * 256 + kc * 64 + g * 8);
            *(uint4*)(s_b + row * 64 + pos * 8) = v;
        }
        __syncthreads();
        #pragma unroll
        for (int ks = 0; ks < 2; ++ks) {
            int g = ks * 4 + q;
            bf16x8 af[2], bfr[8];
            #pragma unroll
            for (int rt = 0; rt < 2; ++rt) {
                int row = w * 32 + rt * 16 + c0;
                af[rt] = *(const bf16x8*)(s_a + row * 64 + (g ^ (row & 7)) * 8);
            }
            #pragma unroll
            for (int ct = 0; ct < 8; ++ct) {
                int row = ct * 16 + c0;
                bfr[ct] = *(const bf16x8*)(s_b + row * 64 + (g ^ (row & 7)) * 8);
            }
            #pragma unroll
            for (int rt = 0; rt < 2; ++rt)
                #pragma unroll
                for (int ct = 0; ct < 8; ++ct)
                    acc[rt][ct] = __builtin_amdgcn_mfma_f32_16x16x32_bf16(
                        af[rt], bfr[ct], acc[rt][ct], 0, 0, 0);
        }
    }

    // epilogue: C layout col = ct*16 + c0, row-in-tile = q*4 + reg
    #pragma unroll
    for (int rt = 0; rt < 2; ++rt) {
        #pragma unroll
        for (int reg = 0; reg < 4; ++reg) {
            int nd = n0 + w * 32 + rt * 16 + q * 4 + reg;
            if (nd >= N_NODES) continue;
            float o[8];
            float s = 0.f;
            #pragma unroll
            for (int ct = 0; ct < 8; ++ct) {
                int col = ct * 16 + c0;
                float v = acc[rt][ct][reg] + s_bl[col] + hres[(size_t)nd * HID + col];
                v = fmaxf(v, 0.f);
                o[ct] = v;
                s += v;
                if (mode == 1) h[(size_t)nd * HID + col] = v;
            }
            if (mode == 1) {
                #pragma unroll
                for (int off = 1; off < 16; off <<= 1) s += __shfl_xor(s, off, 64);
                float mu = s * (1.0f / HID);
                float qs = 0.f;
                #pragma unroll
                for (int ct = 0; ct < 8; ++ct) { float d = o[ct] - mu; qs += d * d; }
                #pragma unroll
                for (int off = 1; off < 16; off <<= 1) qs += __shfl_xor(qs, off, 64);
                float rstd = rsqrtf(qs * (1.0f / HID) + LN_EPS);
                #pragma unroll
                for (int ct = 0; ct < 8; ++ct) {
                    int col = ct * 16 + c0;
                    float hv = (o[ct] - mu) * rstd * s_g[col] + s_bb[col];
                    ahn[(size_t)nd * 256 + 128 + col] = f2bf(hv);
                }
            } else {
                float od0 = 0.f, od1 = 0.f, od2 = 0.f, od3 = 0.f;
                #pragma unroll
                for (int ct = 0; ct < 8; ++ct) {
                    int col = ct * 16 + c0;
                    float v = o[ct];
                    od0 += v * s_wo[col * 4 + 0];
                    od1 += v * s_wo[col * 4 + 1];
                    od2 += v * s_wo[col * 4 + 2];
                    od3 += v * s_wo[col * 4 + 3];
                }
                #pragma unroll
                for (int off = 1; off < 16; off <<= 1) {
                    od0 += __shfl_xor(od0, off, 64);
                    od1 += __shfl_xor(od1, off, 64);
                    od2 += __shfl_xor(od2, off, 64);
                    od3 += __shfl_xor(od3, off, 64);
                }
                if (c0 == 0) {
                    float4 r;
                    r.x = od0 + s_bo[0]; r.y = od1 + s_bo[1];
                    r.z = od2 + s_bo[2]; r.w = od3 + s_bo[3];
                    *(float4*)(out + (size_t)nd * D_OUT) = r;
                }
            }
        }
    }
}

extern "C" void kernel_launch(void* const* d_in, const int* in_sizes, int n_in,
                              void* d_out, int out_size, void* d_ws, size_t ws_size,
                              hipStream_t stream) {
    const float* x    = (const float*)d_in[0];
    const int*   ei   = (const int*)d_in[1];
    const float* W_in = (const float*)d_in[2];
    const float* b_in = (const float*)d_in[3];
    const float* Wl   = (const float*)d_in[4];
    const float* bl   = (const float*)d_in[5];
    const float* Wr   = (const float*)d_in[6];
    const float* ln_g = (const float*)d_in[7];
    const float* ln_b = (const float*)d_in[8];
    const float* W_out= (const float*)d_in[9];
    const float* b_out= (const float*)d_in[10];
    float* out = (float*)d_out;

    float* ws = (float*)d_ws;
    float* h            = ws;                                    // N*128 f32
    unsigned short* ahn = (unsigned short*)(h + (size_t)N_NODES * HID);  // [N][256] bf16
    unsigned short* BT  = ahn + (size_t)N_NODES * 256;           // 3*128*256 bf16
    int*   cursor = (int*)(BT + (size_t)N_LAYERS * 128 * 256);   // N*16 ints (memset)
    int*   ell_t  = cursor + (size_t)N_NODES * CURS;             // 48*N ints, slot-major

    const int* src = ei;
    const int* dst = ei + N_EDGES;

    hipMemsetAsync(cursor, 0, (size_t)N_NODES * CURS * sizeof(int), stream);

    fill_kernel<<<NB_FILL, 256, 0, stream>>>(src, dst, cursor, ell_t);
    winp_kernel<<<NB_W + NB_IN, 256, 0, stream>>>(
        Wl, Wr, BT, x, W_in, b_in, ln_g, ln_b, h, ahn);

    for (int i = 0; i < N_LAYERS; ++i) {
        gather_kernel<<<(N_NODES + 15) / 16, 256, 0, stream>>>(cursor, ell_t, ahn);
        int mode = (i + 1 < N_LAYERS) ? 1 : 2;
        const float* g_next = ln_g + (mode == 1 ? (size_t)(i + 1) * HID : 0);
        const float* b_next = ln_b + (mode == 1 ? (size_t)(i + 1) * HID : 0);
        conv_mfma_kernel<<<(N_NODES + 127) / 128, 256, 0, stream>>>(
            h, ahn, BT + (size_t)i * 128 * 256, bl + i * HID,
            g_next, b_next, h, W_out, b_out, out, mode);
    }
}

// Round 13
// 298.528 us; speedup vs baseline: 1.1701x; 1.1701x over previous
//
#include <hip/hip_runtime.h>

#define N_NODES 50000
#define N_EDGES 800000
#define D_IN 16
#define HID 128
#define D_OUT 4
#define N_LAYERS 3
#define LN_EPS 1e-5f
#define ELL_CAP 48
#define NB_FILL ((N_EDGES + 255) / 256)       // 3125
#define NB_W    (N_LAYERS * 128)              // 384
#define NB_IN   ((N_NODES + 3) / 4)           // 12500

typedef __attribute__((ext_vector_type(8))) short bf16x8;
typedef __attribute__((ext_vector_type(4))) float f32x4;
typedef __attribute__((ext_vector_type(2))) float f32x2;

__device__ __forceinline__ unsigned short f2bf(float f) {
    union { float f; unsigned int u; } a; a.f = f;
    unsigned int r = a.u + 0x7fffu + ((a.u >> 16) & 1u);   // RNE
    return (unsigned short)(r >> 16);
}
__device__ __forceinline__ unsigned int pack2(float x, float y) {
    return (unsigned int)f2bf(x) | ((unsigned int)f2bf(y) << 16);
}
__device__ __forceinline__ float bf2f(unsigned short u) {
    union { unsigned int u; float f; } c; c.u = (unsigned int)u << 16; return c.f;
}

// ---- prep: ELL fill + weight transpose + in_proj/LN (h bf16, hn bf16+fp8) ----
__global__ __launch_bounds__(256) void prep_kernel(
        const int* __restrict__ src, const int* __restrict__ dst,
        int* __restrict__ cursor, int* __restrict__ ell,
        const float* __restrict__ Wl, const float* __restrict__ Wr,
        unsigned short* __restrict__ BT,
        const float* __restrict__ x, const float* __restrict__ W_in,
        const float* __restrict__ b_in,
        const float* __restrict__ g0, const float* __restrict__ bb0,
        unsigned short* __restrict__ h, unsigned short* __restrict__ ahn,
        unsigned char* __restrict__ hn8) {
    int b = blockIdx.x, t = threadIdx.x;
    if (b < NB_FILL) {                        // ELL fill (single edge pass)
        int e = b * 256 + t;
        if (e < N_EDGES) {
            int d = dst[e];
            int slot = atomicAdd(&cursor[d], 1);
            if (slot < ELL_CAP) ell[(size_t)d * ELL_CAP + slot] = src[e];
        }
        return;
    }
    b -= NB_FILL;
    if (b < NB_W) {                           // BT[i][n][k]
        int i = b >> 7, n = b & 127;
        float v = (t < 128) ? Wl[((size_t)i * 128 + t) * 128 + n]
                            : Wr[((size_t)i * 128 + (t - 128)) * 128 + n];
        BT[((size_t)i * 128 + n) * 256 + t] = f2bf(v);
        return;
    }
    b -= NB_W;                                // in_proj + first LN
    int wave = t >> 6, lane = t & 63;
    int node = b * 4 + wave;
    if (node >= N_NODES) return;
    int j0 = lane * 2;
    float a0 = b_in[j0], a1 = b_in[j0 + 1];
    const float* xr = x + (size_t)node * D_IN;
    #pragma unroll
    for (int k = 0; k < D_IN; ++k) {
        float xv = xr[k];
        float2 w = *(const float2*)(W_in + k * HID + j0);
        a0 += xv * w.x;
        a1 += xv * w.y;
    }
    ((unsigned int*)h)[(size_t)node * 64 + lane] = pack2(a0, a1);   // residual, bf16
    float s = a0 + a1;
    #pragma unroll
    for (int o = 32; o > 0; o >>= 1) s += __shfl_xor(s, o, 64);
    float mu = s * (1.0f / HID);
    float d0 = a0 - mu, d1 = a1 - mu;
    float q = d0 * d0 + d1 * d1;
    #pragma unroll
    for (int o = 32; o > 0; o >>= 1) q += __shfl_xor(q, o, 64);
    float rstd = rsqrtf(q * (1.0f / HID) + LN_EPS);
    float2 gg = *(const float2*)(g0 + j0);
    float2 bb = *(const float2*)(bb0 + j0);
    float h0 = d0 * rstd * gg.x + bb.x;
    float h1 = d1 * rstd * gg.y + bb.y;
    ((unsigned int*)(ahn + (size_t)node * 256))[64 + lane] = pack2(h0, h1);
    int r8 = __builtin_amdgcn_cvt_pk_fp8_f32(h0, h1, 0, false);
    *(unsigned short*)(hn8 + (size_t)node * 128 + j0) = (unsigned short)(r8 & 0xffff);
}

// ---- agg half of ahn[n] = bf16( mean hn_fp8[src] ) from ELL rows
//      quarter-wave per node, uint2 fp8 loads (128 B/edge), 8 edges in flight ----
__global__ __launch_bounds__(256) void gather_kernel(
        const int* __restrict__ cursor, const int* __restrict__ ell,
        const unsigned char* __restrict__ hn8, unsigned short* __restrict__ ahn) {
    int tid = threadIdx.x;
    int node = blockIdx.x * 16 + (tid >> 4);
    if (node >= N_NODES) return;
    int l = tid & 15;
    int qbase = (tid & 63) & ~15;
    const uint2* base = (const uint2*)hn8;      // node stride = 16 uint2
    const int* row = ell + (size_t)node * ELL_CAP;
    int cnt = cursor[node];
    int m = cnt < ELL_CAP ? cnt : ELL_CAP;
    float a[8];
    #pragma unroll
    for (int j = 0; j < 8; ++j) a[j] = 0.f;
    int i = 0;
    for (; i + 8 <= m; i += 8) {
        int sv = row[i + (l & 7)];              // lane qbase+j holds row[i + (j&7)]
        uint2 vv[8];
        #pragma unroll
        for (int j = 0; j < 8; ++j) {
            int s = __shfl(sv, qbase + j, 64);
            vv[j] = base[(size_t)s * 16 + l];
        }
        #pragma unroll
        for (int j = 0; j < 8; ++j) {
            f32x2 p0 = __builtin_amdgcn_cvt_pk_f32_fp8((int)vv[j].x, false);
            f32x2 p1 = __builtin_amdgcn_cvt_pk_f32_fp8((int)vv[j].x, true);
            f32x2 p2 = __builtin_amdgcn_cvt_pk_f32_fp8((int)vv[j].y, false);
            f32x2 p3 = __builtin_amdgcn_cvt_pk_f32_fp8((int)vv[j].y, true);
            a[0] += p0.x; a[1] += p0.y; a[2] += p1.x; a[3] += p1.y;
            a[4] += p2.x; a[5] += p2.y; a[6] += p3.x; a[7] += p3.y;
        }
    }
    for (; i + 4 <= m; i += 4) {
        int sv = row[i + (l & 3)];
        uint2 vv[4];
        #pragma unroll
        for (int j = 0; j < 4; ++j) {
            int s = __shfl(sv, qbase + j, 64);
            vv[j] = base[(size_t)s * 16 + l];
        }
        #pragma unroll
        for (int j = 0; j < 4; ++j) {
            f32x2 p0 = __builtin_amdgcn_cvt_pk_f32_fp8((int)vv[j].x, false);
            f32x2 p1 = __builtin_amdgcn_cvt_pk_f32_fp8((int)vv[j].x, true);
            f32x2 p2 = __builtin_amdgcn_cvt_pk_f32_fp8((int)vv[j].y, false);
            f32x2 p3 = __builtin_amdgcn_cvt_pk_f32_fp8((int)vv[j].y, true);
            a[0] += p0.x; a[1] += p0.y; a[2] += p1.x; a[3] += p1.y;
            a[4] += p2.x; a[5] += p2.y; a[6] += p3.x; a[7] += p3.y;
        }
    }
    for (; i < m; ++i) {
        uint2 v = base[(size_t)row[i] * 16 + l];
        f32x2 p0 = __builtin_amdgcn_cvt_pk_f32_fp8((int)v.x, false);
        f32x2 p1 = __builtin_amdgcn_cvt_pk_f32_fp8((int)v.x, true);
        f32x2 p2 = __builtin_amdgcn_cvt_pk_f32_fp8((int)v.y, false);
        f32x2 p3 = __builtin_amdgcn_cvt_pk_f32_fp8((int)v.y, true);
        a[0] += p0.x; a[1] += p0.y; a[2] += p1.x; a[3] += p1.y;
        a[4] += p2.x; a[5] += p2.y; a[6] += p3.x; a[7] += p3.y;
    }
    float inv = 1.0f / fmaxf((float)cnt, 1.0f);
    uint4 o;
    o.x = pack2(a[0] * inv, a[1] * inv);
    o.y = pack2(a[2] * inv, a[3] * inv);
    o.z = pack2(a[4] * inv, a[5] * inv);
    o.w = pack2(a[6] * inv, a[7] * inv);
    ((uint4*)ahn)[(size_t)node * 32 + l] = o;   // agg half (cols 8l..8l+7)
}

// ---- conv: D = ahn(128x256 bf16) @ BT^T; relu(hres + D + bl);
//      mode 1: write h (bf16) + next-layer LN -> ahn hn-half (bf16) + hn8 (fp8)
//      mode 2: fused out-projection (no h write) ----
__global__ __launch_bounds__(256) void conv_mfma_kernel(
        const unsigned short* __restrict__ hres, unsigned short* __restrict__ ahn,
        const unsigned short* __restrict__ BT, const float* __restrict__ bl,
        const float* __restrict__ lng, const float* __restrict__ lnb,
        unsigned short* __restrict__ h, unsigned char* __restrict__ hn8,
        const float* __restrict__ Wout, const float* __restrict__ bout,
        float* __restrict__ out, int mode) {
    __shared__ unsigned short s_a[128 * 64];   // 16 KB, XOR-swizzled 16B groups
    __shared__ unsigned short s_b[128 * 64];   // 16 KB
    __shared__ float s_bl[128], s_g[128], s_bb[128];
    __shared__ float s_wo[512];
    __shared__ float s_bo[4];
    int tid = threadIdx.x;
    int n0 = blockIdx.x * 128;
    if (tid < 128) {
        s_bl[tid] = bl[tid];
        s_g[tid]  = (mode == 1) ? lng[tid] : 0.f;
        s_bb[tid] = (mode == 1) ? lnb[tid] : 0.f;
    }
    if (mode == 2) {
        s_wo[tid]       = Wout[tid];
        s_wo[tid + 256] = Wout[tid + 256];
        if (tid < 4) s_bo[tid] = bout[tid];
    }
    int w = tid >> 6, lane = tid & 63;
    int q = lane >> 4, c0 = lane & 15;

    f32x4 acc[2][8];
    #pragma unroll
    for (int rt = 0; rt < 2; ++rt)
        #pragma unroll
        for (int ct = 0; ct < 8; ++ct) acc[rt][ct] = (f32x4){0.f, 0.f, 0.f, 0.f};

    for (int kc = 0; kc < 4; ++kc) {
        if (kc) __syncthreads();
        #pragma unroll
        for (int p = 0; p < 4; ++p) {      // stage A chunk
            int f = p * 256 + tid;
            int row = f >> 3, g = f & 7;
            int pos = g ^ (row & 7);
            uint4 v = {0u, 0u, 0u, 0u};
            int node = n0 + row;
            if (node < N_NODES)
                v = *(const uint4*)(ahn + (size_t)node * 256 + kc * 64 + g * 8);
            *(uint4*)(s_a + row * 64 + pos * 8) = v;
        }
        #pragma unroll
        for (int p = 0; p < 4; ++p) {      // stage B chunk
            int f = p * 256 + tid;
            int row = f >> 3, g = f & 7;
            int pos = g ^ (row & 7);
            uint4 v = *(const uint4*)(BT + (size_t)row * 256 + kc * 64 + g * 8);
            *(uint4*)(s_b + row * 64 + pos * 8) = v;
        }
        __syncthreads();
        #pragma unroll
        for (int ks = 0; ks < 2; ++ks) {
            int g = ks * 4 + q;
            bf16x8 af[2], bfr[8];
            #pragma unroll
            for (int rt = 0; rt < 2; ++rt) {
                int row = w * 32 + rt * 16 + c0;
                af[rt] = *(const bf16x8*)(s_a + row * 64 + (g ^ (row & 7)) * 8);
            }
            #pragma unroll
            for (int ct = 0; ct < 8; ++ct) {
                int row = ct * 16 + c0;
                bfr[ct] = *(const bf16x8*)(s_b + row * 64 + (g ^ (row & 7)) * 8);
            }
            #pragma unroll
            for (int rt = 0; rt < 2; ++rt)
                #pragma unroll
                for (int ct = 0; ct < 8; ++ct)
                    acc[rt][ct] = __builtin_amdgcn_mfma_f32_16x16x32_bf16(
                        af[rt], bfr[ct], acc[rt][ct], 0, 0, 0);
        }
    }

    // epilogue: C layout col = ct*16 + c0, row-in-tile = q*4 + reg
    #pragma unroll
    for (int rt = 0; rt < 2; ++rt) {
        #pragma unroll
        for (int reg = 0; reg < 4; ++reg) {
            int nd = n0 + w * 32 + rt * 16 + q * 4 + reg;
            if (nd >= N_NODES) continue;
            float o[8];
            float s = 0.f;
            #pragma unroll
            for (int ct = 0; ct < 8; ++ct) {
                int col = ct * 16 + c0;
                float v = acc[rt][ct][reg] + s_bl[col] + bf2f(hres[(size_t)nd * HID + col]);
                v = fmaxf(v, 0.f);
                o[ct] = v;
                s += v;
                if (mode == 1) h[(size_t)nd * HID + col] = f2bf(v);
            }
            if (mode == 1) {
                #pragma unroll
                for (int off = 1; off < 16; off <<= 1) s += __shfl_xor(s, off, 64);
                float mu = s * (1.0f / HID);
                float qs = 0.f;
                #pragma unroll
                for (int ct = 0; ct < 8; ++ct) { float d = o[ct] - mu; qs += d * d; }
                #pragma unroll
                for (int off = 1; off < 16; off <<= 1) qs += __shfl_xor(qs, off, 64);
                float rstd = rsqrtf(qs * (1.0f / HID) + LN_EPS);
                #pragma unroll
                for (int ct = 0; ct < 8; ++ct) {
                    int col = ct * 16 + c0;
                    float hv = (o[ct] - mu) * rstd * s_g[col] + s_bb[col];
                    ahn[(size_t)nd * 256 + 128 + col] = f2bf(hv);
                    int r8 = __builtin_amdgcn_cvt_pk_fp8_f32(hv, hv, 0, false);
                    hn8[(size_t)nd * 128 + col] = (unsigned char)(r8 & 0xff);
                }
            } else {
                float od0 = 0.f, od1 = 0.f, od2 = 0.f, od3 = 0.f;
                #pragma unroll
                for (int ct = 0; ct < 8; ++ct) {
                    int col = ct * 16 + c0;
                    float v = o[ct];
                    od0 += v * s_wo[col * 4 + 0];
                    od1 += v * s_wo[col * 4 + 1];
                    od2 += v * s_wo[col * 4 + 2];
                    od3 += v * s_wo[col * 4 + 3];
                }
                #pragma unroll
                for (int off = 1; off < 16; off <<= 1) {
                    od0 += __shfl_xor(od0, off, 64);
                    od1 += __shfl_xor(od1, off, 64);
                    od2 += __shfl_xor(od2, off, 64);
                    od3 += __shfl_xor(od3, off, 64);
                }
                if (c0 == 0) {
                    float4 r;
                    r.x = od0 + s_bo[0]; r.y = od1 + s_bo[1];
                    r.z = od2 + s_bo[2]; r.w = od3 + s_bo[3];
                    *(float4*)(out + (size_t)nd * D_OUT) = r;
                }
            }
        }
    }
}

extern "C" void kernel_launch(void* const* d_in, const int* in_sizes, int n_in,
                              void* d_out, int out_size, void* d_ws, size_t ws_size,
                              hipStream_t stream) {
    const float* x    = (const float*)d_in[0];
    const int*   ei   = (const int*)d_in[1];
    const float* W_in = (const float*)d_in[2];
    const float* b_in = (const float*)d_in[3];
    const float* Wl   = (const float*)d_in[4];
    const float* bl   = (const float*)d_in[5];
    const float* Wr   = (const float*)d_in[6];
    const float* ln_g = (const float*)d_in[7];
    const float* ln_b = (const float*)d_in[8];
    const float* W_out= (const float*)d_in[9];
    const float* b_out= (const float*)d_in[10];
    float* out = (float*)d_out;

    unsigned short* h   = (unsigned short*)d_ws;                 // [N][128] bf16
    unsigned short* ahn = h + (size_t)N_NODES * HID;             // [N][256] bf16
    unsigned short* BT  = ahn + (size_t)N_NODES * 256;           // 3*128*256 bf16
    unsigned char* hn8  = (unsigned char*)(BT + (size_t)N_LAYERS * 128 * 256); // [N][128] fp8
    int*   cursor = (int*)(hn8 + (size_t)N_NODES * 128);         // N ints (memset)
    int*   ell    = cursor + N_NODES;                            // N*48 ints

    const int* src = ei;
    const int* dst = ei + N_EDGES;

    hipMemsetAsync(cursor, 0, N_NODES * sizeof(int), stream);

    prep_kernel<<<NB_FILL + NB_W + NB_IN, 256, 0, stream>>>(
        src, dst, cursor, ell, Wl, Wr, BT, x, W_in, b_in, ln_g, ln_b, h, ahn, hn8);

    for (int i = 0; i < N_LAYERS; ++i) {
        gather_kernel<<<(N_NODES + 15) / 16, 256, 0, stream>>>(cursor, ell, hn8, ahn);
        int mode = (i + 1 < N_LAYERS) ? 1 : 2;
        const float* g_next = ln_g + (mode == 1 ? (size_t)(i + 1) * HID : 0);
        const float* b_next = ln_b + (mode == 1 ? (size_t)(i + 1) * HID : 0);
        conv_mfma_kernel<<<(N_NODES + 127) / 128, 256, 0, stream>>>(
            h, ahn, BT + (size_t)i * 128 * 256, bl + i * HID,
            g_next, b_next, h, hn8, W_out, b_out, out, mode);
    }
}

// Round 14
// 293.100 us; speedup vs baseline: 1.1918x; 1.0185x over previous
//
#include <hip/hip_runtime.h>

#define N_NODES 50000
#define N_EDGES 800000
#define D_IN 16
#define HID 128
#define D_OUT 4
#define N_LAYERS 3
#define LN_EPS 1e-5f
#define ELL_CAP 48
#define NB_FILL ((N_EDGES + 255) / 256)       // 3125
#define NB_W    (N_LAYERS * 128)              // 384
#define NB_IN   ((N_NODES + 3) / 4)           // 12500

typedef __attribute__((ext_vector_type(8))) short bf16x8;
typedef __attribute__((ext_vector_type(4))) float f32x4;
typedef __attribute__((ext_vector_type(2))) float f32x2;

__device__ __forceinline__ unsigned short f2bf(float f) {
    union { float f; unsigned int u; } a; a.f = f;
    unsigned int r = a.u + 0x7fffu + ((a.u >> 16) & 1u);   // RNE
    return (unsigned short)(r >> 16);
}
__device__ __forceinline__ unsigned int pack2(float x, float y) {
    return (unsigned int)f2bf(x) | ((unsigned int)f2bf(y) << 16);
}
__device__ __forceinline__ float bf2f(unsigned short u) {
    union { unsigned int u; float f; } c; c.u = (unsigned int)u << 16; return c.f;
}

// ---- prep: ELL fill (ushort) + weight transpose + in_proj/LN ----
__global__ __launch_bounds__(256) void prep_kernel(
        const int* __restrict__ src, const int* __restrict__ dst,
        int* __restrict__ cursor, unsigned short* __restrict__ ell,
        const float* __restrict__ Wl, const float* __restrict__ Wr,
        unsigned short* __restrict__ BT,
        const float* __restrict__ x, const float* __restrict__ W_in,
        const float* __restrict__ b_in,
        const float* __restrict__ g0, const float* __restrict__ bb0,
        unsigned short* __restrict__ h, unsigned short* __restrict__ hnb,
        unsigned char* __restrict__ a8) {
    int b = blockIdx.x, t = threadIdx.x;
    if (b < NB_FILL) {                        // ELL fill (single edge pass)
        int e = b * 256 + t;
        if (e < N_EDGES) {
            int d = dst[e];
            int slot = atomicAdd(&cursor[d], 1);
            if (slot < ELL_CAP) ell[(size_t)d * ELL_CAP + slot] = (unsigned short)src[e];
        }
        return;
    }
    b -= NB_FILL;
    if (b < NB_W) {                           // BT[i][n][k]
        int i = b >> 7, n = b & 127;
        float v = (t < 128) ? Wl[((size_t)i * 128 + t) * 128 + n]
                            : Wr[((size_t)i * 128 + (t - 128)) * 128 + n];
        BT[((size_t)i * 128 + n) * 256 + t] = f2bf(v);
        return;
    }
    b -= NB_W;                                // in_proj + first LN
    int wave = t >> 6, lane = t & 63;
    int node = b * 4 + wave;
    if (node >= N_NODES) return;
    int j0 = lane * 2;
    float a0 = b_in[j0], a1 = b_in[j0 + 1];
    const float* xr = x + (size_t)node * D_IN;
    #pragma unroll
    for (int k = 0; k < D_IN; ++k) {
        float xv = xr[k];
        float2 w = *(const float2*)(W_in + k * HID + j0);
        a0 += xv * w.x;
        a1 += xv * w.y;
    }
    ((unsigned int*)h)[(size_t)node * 64 + lane] = pack2(a0, a1);   // residual, bf16
    float s = a0 + a1;
    #pragma unroll
    for (int o = 32; o > 0; o >>= 1) s += __shfl_xor(s, o, 64);
    float mu = s * (1.0f / HID);
    float d0 = a0 - mu, d1 = a1 - mu;
    float q = d0 * d0 + d1 * d1;
    #pragma unroll
    for (int o = 32; o > 0; o >>= 1) q += __shfl_xor(q, o, 64);
    float rstd = rsqrtf(q * (1.0f / HID) + LN_EPS);
    float2 gg = *(const float2*)(g0 + j0);
    float2 bb = *(const float2*)(bb0 + j0);
    float h0 = d0 * rstd * gg.x + bb.x;
    float h1 = d1 * rstd * gg.y + bb.y;
    ((unsigned int*)hnb)[(size_t)node * 64 + lane] = pack2(h0, h1);  // bf16 (GEMM)
    int r8 = __builtin_amdgcn_cvt_pk_fp8_f32(h0, h1, 0, false);
    *(unsigned short*)(a8 + (size_t)node * 256 + 128 + j0) = (unsigned short)(r8 & 0xffff);
}

// ---- agg8 half of a8[n] = fp8( mean hn_fp8[src] ) from ELL rows
//      quarter-wave per node, uint2 fp8 loads, 8 edges in flight ----
__global__ __launch_bounds__(256) void gather_kernel(
        const int* __restrict__ cursor, const unsigned short* __restrict__ ell,
        unsigned char* __restrict__ a8) {
    int tid = threadIdx.x;
    int node = blockIdx.x * 16 + (tid >> 4);
    if (node >= N_NODES) return;
    int l = tid & 15;
    int qbase = (tid & 63) & ~15;
    const uint2* base = (const uint2*)a8;       // node stride = 32 uint2; hn half at +16
    const unsigned short* row = ell + (size_t)node * ELL_CAP;
    int cnt = cursor[node];
    int m = cnt < ELL_CAP ? cnt : ELL_CAP;
    float a[8];
    #pragma unroll
    for (int j = 0; j < 8; ++j) a[j] = 0.f;
    int i = 0;
    for (; i + 8 <= m; i += 8) {
        int sv = row[i + (l & 7)];              // lane qbase+j holds row[i + (j&7)]
        uint2 vv[8];
        #pragma unroll
        for (int j = 0; j < 8; ++j) {
            int s = __shfl(sv, qbase + j, 64);
            vv[j] = base[(size_t)s * 32 + 16 + l];
        }
        #pragma unroll
        for (int j = 0; j < 8; ++j) {
            f32x2 p0 = __builtin_amdgcn_cvt_pk_f32_fp8((int)vv[j].x, false);
            f32x2 p1 = __builtin_amdgcn_cvt_pk_f32_fp8((int)vv[j].x, true);
            f32x2 p2 = __builtin_amdgcn_cvt_pk_f32_fp8((int)vv[j].y, false);
            f32x2 p3 = __builtin_amdgcn_cvt_pk_f32_fp8((int)vv[j].y, true);
            a[0] += p0.x; a[1] += p0.y; a[2] += p1.x; a[3] += p1.y;
            a[4] += p2.x; a[5] += p2.y; a[6] += p3.x; a[7] += p3.y;
        }
    }
    for (; i + 4 <= m; i += 4) {
        int sv = row[i + (l & 3)];
        uint2 vv[4];
        #pragma unroll
        for (int j = 0; j < 4; ++j) {
            int s = __shfl(sv, qbase + j, 64);
            vv[j] = base[(size_t)s * 32 + 16 + l];
        }
        #pragma unroll
        for (int j = 0; j < 4; ++j) {
            f32x2 p0 = __builtin_amdgcn_cvt_pk_f32_fp8((int)vv[j].x, false);
            f32x2 p1 = __builtin_amdgcn_cvt_pk_f32_fp8((int)vv[j].x, true);
            f32x2 p2 = __builtin_amdgcn_cvt_pk_f32_fp8((int)vv[j].y, false);
            f32x2 p3 = __builtin_amdgcn_cvt_pk_f32_fp8((int)vv[j].y, true);
            a[0] += p0.x; a[1] += p0.y; a[2] += p1.x; a[3] += p1.y;
            a[4] += p2.x; a[5] += p2.y; a[6] += p3.x; a[7] += p3.y;
        }
    }
    for (; i < m; ++i) {
        uint2 v = base[(size_t)row[i] * 32 + 16 + l];
        f32x2 p0 = __builtin_amdgcn_cvt_pk_f32_fp8((int)v.x, false);
        f32x2 p1 = __builtin_amdgcn_cvt_pk_f32_fp8((int)v.x, true);
        f32x2 p2 = __builtin_amdgcn_cvt_pk_f32_fp8((int)v.y, false);
        f32x2 p3 = __builtin_amdgcn_cvt_pk_f32_fp8((int)v.y, true);
        a[0] += p0.x; a[1] += p0.y; a[2] += p1.x; a[3] += p1.y;
        a[4] += p2.x; a[5] += p2.y; a[6] += p3.x; a[7] += p3.y;
    }
    float inv = 1.0f / fmaxf((float)cnt, 1.0f);
    int r0 = __builtin_amdgcn_cvt_pk_fp8_f32(a[0] * inv, a[1] * inv, 0, false);
    r0     = __builtin_amdgcn_cvt_pk_fp8_f32(a[2] * inv, a[3] * inv, r0, true);
    int r1 = __builtin_amdgcn_cvt_pk_fp8_f32(a[4] * inv, a[5] * inv, 0, false);
    r1     = __builtin_amdgcn_cvt_pk_fp8_f32(a[6] * inv, a[7] * inv, r1, true);
    uint2 o; o.x = (unsigned int)r0; o.y = (unsigned int)r1;
    ((uint2*)a8)[(size_t)node * 32 + l] = o;    // agg8 half (bytes 8l..8l+7)
}

// ---- conv: A = [agg8(fp8) | hnb(bf16)] 128x256; D = A @ BT^T; relu(hres+D+bl)
//      mode 1: write h(bf16) + next-LN -> hnb(bf16) + a8 hn-half(fp8)
//      mode 2: fused out-projection ----
__global__ __launch_bounds__(256) void conv_mfma_kernel(
        const unsigned short* __restrict__ hres, const unsigned char* __restrict__ a8c,
        unsigned char* __restrict__ a8, unsigned short* __restrict__ hnb,
        const unsigned short* __restrict__ BT, const float* __restrict__ bl,
        const float* __restrict__ lng, const float* __restrict__ lnb,
        unsigned short* __restrict__ h,
        const float* __restrict__ Wout, const float* __restrict__ bout,
        float* __restrict__ out, int mode) {
    __shared__ unsigned short s_a[128 * 64];   // 16 KB, XOR-swizzled 16B groups
    __shared__ unsigned short s_b[128 * 64];   // 16 KB
    __shared__ float s_bl[128], s_g[128], s_bb[128];
    __shared__ float s_wo[512];
    __shared__ float s_bo[4];
    int tid = threadIdx.x;
    int n0 = blockIdx.x * 128;
    if (tid < 128) {
        s_bl[tid] = bl[tid];
        s_g[tid]  = (mode == 1) ? lng[tid] : 0.f;
        s_bb[tid] = (mode == 1) ? lnb[tid] : 0.f;
    }
    if (mode == 2) {
        s_wo[tid]       = Wout[tid];
        s_wo[tid + 256] = Wout[tid + 256];
        if (tid < 4) s_bo[tid] = bout[tid];
    }
    int w = tid >> 6, lane = tid & 63;
    int q = lane >> 4, c0 = lane & 15;

    f32x4 acc[2][8];
    #pragma unroll
    for (int rt = 0; rt < 2; ++rt)
        #pragma unroll
        for (int ct = 0; ct < 8; ++ct) acc[rt][ct] = (f32x4){0.f, 0.f, 0.f, 0.f};

    for (int kc = 0; kc < 4; ++kc) {
        if (kc) __syncthreads();
        if (kc < 2) {                      // stage A from agg8 (fp8 -> bf16)
            #pragma unroll
            for (int p = 0; p < 2; ++p) {
                int f = p * 256 + tid;
                int row = f >> 2, j = f & 3;
                uint4 v = {0u, 0u, 0u, 0u};
                int node = n0 + row;
                if (node < N_NODES)
                    v = *(const uint4*)(a8c + (size_t)node * 256 + kc * 64 + j * 16);
                f32x2 p0 = __builtin_amdgcn_cvt_pk_f32_fp8((int)v.x, false);
                f32x2 p1 = __builtin_amdgcn_cvt_pk_f32_fp8((int)v.x, true);
                f32x2 p2 = __builtin_amdgcn_cvt_pk_f32_fp8((int)v.y, false);
                f32x2 p3 = __builtin_amdgcn_cvt_pk_f32_fp8((int)v.y, true);
                uint4 o0;
                o0.x = pack2(p0.x, p0.y); o0.y = pack2(p1.x, p1.y);
                o0.z = pack2(p2.x, p2.y); o0.w = pack2(p3.x, p3.y);
                p0 = __builtin_amdgcn_cvt_pk_f32_fp8((int)v.z, false);
                p1 = __builtin_amdgcn_cvt_pk_f32_fp8((int)v.z, true);
                p2 = __builtin_amdgcn_cvt_pk_f32_fp8((int)v.w, false);
                p3 = __builtin_amdgcn_cvt_pk_f32_fp8((int)v.w, true);
                uint4 o1;
                o1.x = pack2(p0.x, p0.y); o1.y = pack2(p1.x, p1.y);
                o1.z = pack2(p2.x, p2.y); o1.w = pack2(p3.x, p3.y);
                int g0 = 2 * j, g1 = 2 * j + 1;
                *(uint4*)(s_a + row * 64 + (g0 ^ (row & 7)) * 8) = o0;
                *(uint4*)(s_a + row * 64 + (g1 ^ (row & 7)) * 8) = o1;
            }
        } else {                           // stage A from hnb (bf16 direct)
            #pragma unroll
            for (int p = 0; p < 4; ++p) {
                int f = p * 256 + tid;
                int row = f >> 3, g = f & 7;
                int pos = g ^ (row & 7);
                uint4 v = {0u, 0u, 0u, 0u};
                int node = n0 + row;
                if (node < N_NODES)
                    v = *(const uint4*)(hnb + (size_t)node * 128 + (kc - 2) * 64 + g * 8);
                *(uint4*)(s_a + row * 64 + pos * 8) = v;
            }
        }
        #pragma unroll
        for (int p = 0; p < 4; ++p) {      // stage B chunk
            int f = p * 256 + tid;
            int row = f >> 3, g = f & 7;
            int pos = g ^ (row & 7);
            uint4 v = *(const uint4*)(BT + (size_t)row * 256 + kc * 64 + g * 8);
            *(uint4*)(s_b + row * 64 + pos * 8) = v;
        }
        __syncthreads();
        #pragma unroll
        for (int ks = 0; ks < 2; ++ks) {
            int g = ks * 4 + q;
            bf16x8 af[2], bfr[8];
            #pragma unroll
            for (int rt = 0; rt < 2; ++rt) {
                int row = w * 32 + rt * 16 + c0;
                af[rt] = *(const bf16x8*)(s_a + row * 64 + (g ^ (row & 7)) * 8);
            }
            #pragma unroll
            for (int ct = 0; ct < 8; ++ct) {
                int row = ct * 16 + c0;
                bfr[ct] = *(const bf16x8*)(s_b + row * 64 + (g ^ (row & 7)) * 8);
            }
            #pragma unroll
            for (int rt = 0; rt < 2; ++rt)
                #pragma unroll
                for (int ct = 0; ct < 8; ++ct)
                    acc[rt][ct] = __builtin_amdgcn_mfma_f32_16x16x32_bf16(
                        af[rt], bfr[ct], acc[rt][ct], 0, 0, 0);
        }
    }

    // epilogue: C layout col = ct*16 + c0, row-in-tile = q*4 + reg
    #pragma unroll
    for (int rt = 0; rt < 2; ++rt) {
        #pragma unroll
        for (int reg = 0; reg < 4; ++reg) {
            int nd = n0 + w * 32 + rt * 16 + q * 4 + reg;
            if (nd >= N_NODES) continue;
            float o[8];
            float s = 0.f;
            #pragma unroll
            for (int ct = 0; ct < 8; ++ct) {
                int col = ct * 16 + c0;
                float v = acc[rt][ct][reg] + s_bl[col] + bf2f(hres[(size_t)nd * HID + col]);
                v = fmaxf(v, 0.f);
                o[ct] = v;
                s += v;
                if (mode == 1) h[(size_t)nd * HID + col] = f2bf(v);
            }
            if (mode == 1) {
                #pragma unroll
                for (int off = 1; off < 16; off <<= 1) s += __shfl_xor(s, off, 64);
                float mu = s * (1.0f / HID);
                float qs = 0.f;
                #pragma unroll
                for (int ct = 0; ct < 8; ++ct) { float d = o[ct] - mu; qs += d * d; }
                #pragma unroll
                for (int off = 1; off < 16; off <<= 1) qs += __shfl_xor(qs, off, 64);
                float rstd = rsqrtf(qs * (1.0f / HID) + LN_EPS);
                #pragma unroll
                for (int ct = 0; ct < 8; ++ct) {
                    int col = ct * 16 + c0;
                    float hv = (o[ct] - mu) * rstd * s_g[col] + s_bb[col];
                    hnb[(size_t)nd * 128 + col] = f2bf(hv);
                    int r8 = __builtin_amdgcn_cvt_pk_fp8_f32(hv, hv, 0, false);
                    a8[(size_t)nd * 256 + 128 + col] = (unsigned char)(r8 & 0xff);
                }
            } else {
                float od0 = 0.f, od1 = 0.f, od2 = 0.f, od3 = 0.f;
                #pragma unroll
                for (int ct = 0; ct < 8; ++ct) {
                    int col = ct * 16 + c0;
                    float v = o[ct];
                    od0 += v * s_wo[col * 4 + 0];
                    od1 += v * s_wo[col * 4 + 1];
                    od2 += v * s_wo[col * 4 + 2];
                    od3 += v * s_wo[col * 4 + 3];
                }
                #pragma unroll
                for (int off = 1; off < 16; off <<= 1) {
                    od0 += __shfl_xor(od0, off, 64);
                    od1 += __shfl_xor(od1, off, 64);
                    od2 += __shfl_xor(od2, off, 64);
                    od3 += __shfl_xor(od3, off, 64);
                }
                if (c0 == 0) {
                    float4 r;
                    r.x = od0 + s_bo[0]; r.y = od1 + s_bo[1];
                    r.z = od2 + s_bo[2]; r.w = od3 + s_bo[3];
                    *(float4*)(out + (size_t)nd * D_OUT) = r;
                }
            }
        }
    }
}

extern "C" void kernel_launch(void* const* d_in, const int* in_sizes, int n_in,
                              void* d_out, int out_size, void* d_ws, size_t ws_size,
                              hipStream_t stream) {
    const float* x    = (const float*)d_in[0];
    const int*   ei   = (const int*)d_in[1];
    const float* W_in = (const float*)d_in[2];
    const float* b_in = (const float*)d_in[3];
    const float* Wl   = (const float*)d_in[4];
    const float* bl   = (const float*)d_in[5];
    const float* Wr   = (const float*)d_in[6];
    const float* ln_g = (const float*)d_in[7];
    const float* ln_b = (const float*)d_in[8];
    const float* W_out= (const float*)d_in[9];
    const float* b_out= (const float*)d_in[10];
    float* out = (float*)d_out;

    unsigned short* h   = (unsigned short*)d_ws;                 // [N][128] bf16
    unsigned short* hnb = h + (size_t)N_NODES * HID;             // [N][128] bf16
    unsigned short* BT  = hnb + (size_t)N_NODES * HID;           // 3*128*256 bf16
    unsigned char* a8   = (unsigned char*)(BT + (size_t)N_LAYERS * 128 * 256); // [N][256] fp8
    int*   cursor = (int*)(a8 + (size_t)N_NODES * 256);          // N ints (memset)
    unsigned short* ell = (unsigned short*)(cursor + N_NODES);   // N*48 ushort

    const int* src = ei;
    const int* dst = ei + N_EDGES;

    hipMemsetAsync(cursor, 0, N_NODES * sizeof(int), stream);

    prep_kernel<<<NB_FILL + NB_W + NB_IN, 256, 0, stream>>>(
        src, dst, cursor, ell, Wl, Wr, BT, x, W_in, b_in, ln_g, ln_b, h, hnb, a8);

    for (int i = 0; i < N_LAYERS; ++i) {
        gather_kernel<<<(N_NODES + 15) / 16, 256, 0, stream>>>(cursor, ell, a8);
        int mode = (i + 1 < N_LAYERS) ? 1 : 2;
        const float* g_next = ln_g + (mode == 1 ? (size_t)(i + 1) * HID : 0);
        const float* b_next = ln_b + (mode == 1 ? (size_t)(i + 1) * HID : 0);
        conv_mfma_kernel<<<(N_NODES + 127) / 128, 256, 0, stream>>>(
            h, a8, a8, hnb, BT + (size_t)i * 128 * 256, bl + i * HID,
            g_next, b_next, h, W_out, b_out, out, mode);
    }
}

// Round 15
// 287.036 us; speedup vs baseline: 1.2170x; 1.0211x over previous
//
#include <hip/hip_runtime.h>

#define N_NODES 50000
#define N_EDGES 800000
#define D_IN 16
#define HID 128
#define D_OUT 4
#define N_LAYERS 3
#define LN_EPS 1e-5f
#define ELL_CAP 48
#define NBUCK 196                             // dst >> 8 buckets
#define BCAP 5120                             // bucket region capacity (mean 4082, sigma 64)
#define NBLK_E (N_EDGES / 256)                // 3125, exact
#define NB_W    (N_LAYERS * 128)              // 384
#define NB_IN   ((N_NODES + 3) / 4)           // 12500

typedef __attribute__((ext_vector_type(8))) short bf16x8;
typedef __attribute__((ext_vector_type(4))) float f32x4;
typedef __attribute__((ext_vector_type(2))) float f32x2;

__device__ __forceinline__ unsigned short f2bf(float f) {
    union { float f; unsigned int u; } a; a.f = f;
    unsigned int r = a.u + 0x7fffu + ((a.u >> 16) & 1u);   // RNE
    return (unsigned short)(r >> 16);
}
__device__ __forceinline__ unsigned int pack2(float x, float y) {
    return (unsigned int)f2bf(x) | ((unsigned int)f2bf(y) << 16);
}
__device__ __forceinline__ float bf2f(unsigned short u) {
    union { unsigned int u; float f; } c; c.u = (unsigned int)u << 16; return c.f;
}

// ---- A: bucket histogram + weight transpose + in_proj/LN, one dispatch ----
__global__ __launch_bounds__(256) void prep_kernel(
        const int* __restrict__ dst, int* __restrict__ histM,
        const float* __restrict__ Wl, const float* __restrict__ Wr,
        unsigned short* __restrict__ BT,
        const float* __restrict__ x, const float* __restrict__ W_in,
        const float* __restrict__ b_in,
        const float* __restrict__ g0, const float* __restrict__ bb0,
        unsigned short* __restrict__ h, unsigned short* __restrict__ hnb,
        unsigned char* __restrict__ a8) {
    int b = blockIdx.x, t = threadIdx.x;
    if (b < NBLK_E) {                         // bucket histogram (LDS only)
        __shared__ int cnt[NBUCK];
        if (t < NBUCK) cnt[t] = 0;
        __syncthreads();
        int d = dst[b * 256 + t];             // 800000 = 3125*256 exact
        atomicAdd(&cnt[d >> 8], 1);
        __syncthreads();
        if (t < NBUCK) histM[(size_t)b * NBUCK + t] = cnt[t];
        return;
    }
    b -= NBLK_E;
    if (b < NB_W) {                           // BT[i][n][k]
        int i = b >> 7, n = b & 127;
        float v = (t < 128) ? Wl[((size_t)i * 128 + t) * 128 + n]
                            : Wr[((size_t)i * 128 + (t - 128)) * 128 + n];
        BT[((size_t)i * 128 + n) * 256 + t] = f2bf(v);
        return;
    }
    b -= NB_W;                                // in_proj + first LN
    int wave = t >> 6, lane = t & 63;
    int node = b * 4 + wave;
    if (node >= N_NODES) return;
    int j0 = lane * 2;
    float a0 = b_in[j0], a1 = b_in[j0 + 1];
    const float* xr = x + (size_t)node * D_IN;
    #pragma unroll
    for (int k = 0; k < D_IN; ++k) {
        float xv = xr[k];
        float2 w = *(const float2*)(W_in + k * HID + j0);
        a0 += xv * w.x;
        a1 += xv * w.y;
    }
    ((unsigned int*)h)[(size_t)node * 64 + lane] = pack2(a0, a1);   // residual, bf16
    float s = a0 + a1;
    #pragma unroll
    for (int o = 32; o > 0; o >>= 1) s += __shfl_xor(s, o, 64);
    float mu = s * (1.0f / HID);
    float d0 = a0 - mu, d1 = a1 - mu;
    float q = d0 * d0 + d1 * d1;
    #pragma unroll
    for (int o = 32; o > 0; o >>= 1) q += __shfl_xor(q, o, 64);
    float rstd = rsqrtf(q * (1.0f / HID) + LN_EPS);
    float2 gg = *(const float2*)(g0 + j0);
    float2 bb = *(const float2*)(bb0 + j0);
    float h0 = d0 * rstd * gg.x + bb.x;
    float h1 = d1 * rstd * gg.y + bb.y;
    ((unsigned int*)hnb)[(size_t)node * 64 + lane] = pack2(h0, h1);  // bf16 (GEMM)
    int r8 = __builtin_amdgcn_cvt_pk_fp8_f32(h0, h1, 0, false);
    *(unsigned short*)(a8 + (size_t)node * 256 + 128 + j0) = (unsigned short)(r8 & 0xffff);
}

// ---- B: per-bucket exclusive scan over blocks; histM <- global base offsets ----
__global__ __launch_bounds__(256) void scan_kernel(int* __restrict__ histM,
                                                   int* __restrict__ btotal) {
    __shared__ int s[256];
    int b = blockIdx.x, t = threadIdx.x;
    const int CH = (NBLK_E + 255) / 256;      // 13
    int base = t * CH;
    int lsum = 0;
    for (int i = 0; i < CH; ++i) {
        int k = base + i;
        if (k < NBLK_E) lsum += histM[(size_t)k * NBUCK + b];
    }
    s[t] = lsum;
    __syncthreads();
    for (int off = 1; off < 256; off <<= 1) {
        int u = (t >= off) ? s[t - off] : 0;
        __syncthreads();
        s[t] += u;
        __syncthreads();
    }
    int running = (t == 0) ? 0 : s[t - 1];
    for (int i = 0; i < CH; ++i) {
        int k = base + i;
        if (k < NBLK_E) {
            int tmp = histM[(size_t)k * NBUCK + b];
            histM[(size_t)k * NBUCK + b] = running;
            running += tmp;
        }
    }
    if (t == 255) btotal[b] = running;
}

// ---- C: scatter edges into bucket regions (LDS cursors, no global atomics) ----
__global__ __launch_bounds__(256) void scat_kernel(
        const int* __restrict__ src, const int* __restrict__ dst,
        const int* __restrict__ histM, unsigned int* __restrict__ part) {
    __shared__ int cur[NBUCK];
    int b = blockIdx.x, t = threadIdx.x;
    if (t < NBUCK) cur[t] = histM[(size_t)b * NBUCK + t];
    __syncthreads();
    int e = b * 256 + t;
    int d = dst[e];
    int bk = d >> 8;
    int pos = atomicAdd(&cur[bk], 1);         // LDS atomic
    if (pos < BCAP)
        part[(size_t)bk * BCAP + pos] =
            (unsigned int)src[e] | ((unsigned int)(d & 255) << 16);
}

// ---- D: per-bucket ELL build (LDS slot counters) + cursor counts ----
__global__ __launch_bounds__(256) void ell_kernel(
        const unsigned int* __restrict__ part, const int* __restrict__ btotal,
        unsigned short* __restrict__ ell, int* __restrict__ cursor) {
    __shared__ int cnt[256];
    int b = blockIdx.x, t = threadIdx.x;
    cnt[t] = 0;
    __syncthreads();
    int total = btotal[b];
    if (total > BCAP) total = BCAP;
    int n0 = b * 256;
    for (int i = t; i < total; i += 256) {
        unsigned int rec = part[(size_t)b * BCAP + i];
        int dl = rec >> 16;
        int slot = atomicAdd(&cnt[dl], 1);    // LDS atomic
        if (slot < ELL_CAP)
            ell[(size_t)(n0 + dl) * ELL_CAP + slot] = (unsigned short)(rec & 0xffff);
    }
    __syncthreads();
    int n = n0 + t;
    if (n < N_NODES) cursor[n] = cnt[t];
}

// ---- agg8 half of a8[n] = fp8( mean hn_fp8[src] ) from ELL rows
//      quarter-wave per node, uint2 fp8 loads, 8 edges in flight ----
__global__ __launch_bounds__(256) void gather_kernel(
        const int* __restrict__ cursor, const unsigned short* __restrict__ ell,
        unsigned char* __restrict__ a8) {
    int tid = threadIdx.x;
    int node = blockIdx.x * 16 + (tid >> 4);
    if (node >= N_NODES) return;
    int l = tid & 15;
    int qbase = (tid & 63) & ~15;
    const uint2* base = (const uint2*)a8;       // node stride = 32 uint2; hn half at +16
    const unsigned short* row = ell + (size_t)node * ELL_CAP;
    int cnt = cursor[node];
    int m = cnt < ELL_CAP ? cnt : ELL_CAP;
    float a[8];
    #pragma unroll
    for (int j = 0; j < 8; ++j) a[j] = 0.f;
    int i = 0;
    for (; i + 8 <= m; i += 8) {
        int sv = row[i + (l & 7)];              // lane qbase+j holds row[i + (j&7)]
        uint2 vv[8];
        #pragma unroll
        for (int j = 0; j < 8; ++j) {
            int s = __shfl(sv, qbase + j, 64);
            vv[j] = base[(size_t)s * 32 + 16 + l];
        }
        #pragma unroll
        for (int j = 0; j < 8; ++j) {
            f32x2 p0 = __builtin_amdgcn_cvt_pk_f32_fp8((int)vv[j].x, false);
            f32x2 p1 = __builtin_amdgcn_cvt_pk_f32_fp8((int)vv[j].x, true);
            f32x2 p2 = __builtin_amdgcn_cvt_pk_f32_fp8((int)vv[j].y, false);
            f32x2 p3 = __builtin_amdgcn_cvt_pk_f32_fp8((int)vv[j].y, true);
            a[0] += p0.x; a[1] += p0.y; a[2] += p1.x; a[3] += p1.y;
            a[4] += p2.x; a[5] += p2.y; a[6] += p3.x; a[7] += p3.y;
        }
    }
    for (; i + 4 <= m; i += 4) {
        int sv = row[i + (l & 3)];
        uint2 vv[4];
        #pragma unroll
        for (int j = 0; j < 4; ++j) {
            int s = __shfl(sv, qbase + j, 64);
            vv[j] = base[(size_t)s * 32 + 16 + l];
        }
        #pragma unroll
        for (int j = 0; j < 4; ++j) {
            f32x2 p0 = __builtin_amdgcn_cvt_pk_f32_fp8((int)vv[j].x, false);
            f32x2 p1 = __builtin_amdgcn_cvt_pk_f32_fp8((int)vv[j].x, true);
            f32x2 p2 = __builtin_amdgcn_cvt_pk_f32_fp8((int)vv[j].y, false);
            f32x2 p3 = __builtin_amdgcn_cvt_pk_f32_fp8((int)vv[j].y, true);
            a[0] += p0.x; a[1] += p0.y; a[2] += p1.x; a[3] += p1.y;
            a[4] += p2.x; a[5] += p2.y; a[6] += p3.x; a[7] += p3.y;
        }
    }
    for (; i < m; ++i) {
        uint2 v = base[(size_t)row[i] * 32 + 16 + l];
        f32x2 p0 = __builtin_amdgcn_cvt_pk_f32_fp8((int)v.x, false);
        f32x2 p1 = __builtin_amdgcn_cvt_pk_f32_fp8((int)v.x, true);
        f32x2 p2 = __builtin_amdgcn_cvt_pk_f32_fp8((int)v.y, false);
        f32x2 p3 = __builtin_amdgcn_cvt_pk_f32_fp8((int)v.y, true);
        a[0] += p0.x; a[1] += p0.y; a[2] += p1.x; a[3] += p1.y;
        a[4] += p2.x; a[5] += p2.y; a[6] += p3.x; a[7] += p3.y;
    }
    float inv = 1.0f / fmaxf((float)cnt, 1.0f);
    int r0 = __builtin_amdgcn_cvt_pk_fp8_f32(a[0] * inv, a[1] * inv, 0, false);
    r0     = __builtin_amdgcn_cvt_pk_fp8_f32(a[2] * inv, a[3] * inv, r0, true);
    int r1 = __builtin_amdgcn_cvt_pk_fp8_f32(a[4] * inv, a[5] * inv, 0, false);
    r1     = __builtin_amdgcn_cvt_pk_fp8_f32(a[6] * inv, a[7] * inv, r1, true);
    uint2 o; o.x = (unsigned int)r0; o.y = (unsigned int)r1;
    ((uint2*)a8)[(size_t)node * 32 + l] = o;    // agg8 half (bytes 8l..8l+7)
}

// ---- conv: A = [agg8(fp8) | hnb(bf16)] 128x256; D = A @ BT^T; relu(hres+D+bl)
//      mode 1: write h(bf16) + next-LN -> hnb(bf16) + a8 hn-half(fp8)
//      mode 2: fused out-projection ----
__global__ __launch_bounds__(256) void conv_mfma_kernel(
        const unsigned short* __restrict__ hres, const unsigned char* __restrict__ a8c,
        unsigned char* __restrict__ a8, unsigned short* __restrict__ hnb,
        const unsigned short* __restrict__ BT, const float* __restrict__ bl,
        const float* __restrict__ lng, const float* __restrict__ lnb,
        unsigned short* __restrict__ h,
        const float* __restrict__ Wout, const float* __restrict__ bout,
        float* __restrict__ out, int mode) {
    __shared__ unsigned short s_a[128 * 64];   // 16 KB, XOR-swizzled 16B groups
    __shared__ unsigned short s_b[128 * 64];   // 16 KB
    __shared__ float s_bl[128], s_g[128], s_bb[128];
    __shared__ float s_wo[512];
    __shared__ float s_bo[4];
    int tid = threadIdx.x;
    int n0 = blockIdx.x * 128;
    if (tid < 128) {
        s_bl[tid] = bl[tid];
        s_g[tid]  = (mode == 1) ? lng[tid] : 0.f;
        s_bb[tid] = (mode == 1) ? lnb[tid] : 0.f;
    }
    if (mode == 2) {
        s_wo[tid]       = Wout[tid];
        s_wo[tid + 256] = Wout[tid + 256];
        if (tid < 4) s_bo[tid] = bout[tid];
    }
    int w = tid >> 6, lane = tid & 63;
    int q = lane >> 4, c0 = lane & 15;

    f32x4 acc[2][8];
    #pragma unroll
    for (int rt = 0; rt < 2; ++rt)
        #pragma unroll
        for (int ct = 0; ct < 8; ++ct) acc[rt][ct] = (f32x4){0.f, 0.f, 0.f, 0.f};

    for (int kc = 0; kc < 4; ++kc) {
        if (kc) __syncthreads();
        if (kc < 2) {                      // stage A from agg8 (fp8 -> bf16)
            #pragma unroll
            for (int p = 0; p < 2; ++p) {
                int f = p * 256 + tid;
                int row = f >> 2, j = f & 3;
                uint4 v = {0u, 0u, 0u, 0u};
                int node = n0 + row;
                if (node < N_NODES)
                    v = *(const uint4*)(a8c + (size_t)node * 256 + kc * 64 + j * 16);
                f32x2 p0 = __builtin_amdgcn_cvt_pk_f32_fp8((int)v.x, false);
                f32x2 p1 = __builtin_amdgcn_cvt_pk_f32_fp8((int)v.x, true);
                f32x2 p2 = __builtin_amdgcn_cvt_pk_f32_fp8((int)v.y, false);
                f32x2 p3 = __builtin_amdgcn_cvt_pk_f32_fp8((int)v.y, true);
                uint4 o0;
                o0.x = pack2(p0.x, p0.y); o0.y = pack2(p1.x, p1.y);
                o0.z = pack2(p2.x, p2.y); o0.w = pack2(p3.x, p3.y);
                p0 = __builtin_amdgcn_cvt_pk_f32_fp8((int)v.z, false);
                p1 = __builtin_amdgcn_cvt_pk_f32_fp8((int)v.z, true);
                p2 = __builtin_amdgcn_cvt_pk_f32_fp8((int)v.w, false);
                p3 = __builtin_amdgcn_cvt_pk_f32_fp8((int)v.w, true);
                uint4 o1;
                o1.x = pack2(p0.x, p0.y); o1.y = pack2(p1.x, p1.y);
                o1.z = pack2(p2.x, p2.y); o1.w = pack2(p3.x, p3.y);
                int g0 = 2 * j, g1 = 2 * j + 1;
                *(uint4*)(s_a + row * 64 + (g0 ^ (row & 7)) * 8) = o0;
                *(uint4*)(s_a + row * 64 + (g1 ^ (row & 7)) * 8) = o1;
            }
        } else {                           // stage A from hnb (bf16 direct)
            #pragma unroll
            for (int p = 0; p < 4; ++p) {
                int f = p * 256 + tid;
                int row = f >> 3, g = f & 7;
                int pos = g ^ (row & 7);
                uint4 v = {0u, 0u, 0u, 0u};
                int node = n0 + row;
                if (node < N_NODES)
                    v = *(const uint4*)(hnb + (size_t)node * 128 + (kc - 2) * 64 + g * 8);
                *(uint4*)(s_a + row * 64 + pos * 8) = v;
            }
        }
        #pragma unroll
        for (int p = 0; p < 4; ++p) {      // stage B chunk
            int f = p * 256 + tid;
            int row = f >> 3, g = f & 7;
            int pos = g ^ (row & 7);
            uint4 v = *(const uint4*)(BT + (size_t)row * 256 + kc * 64 + g * 8);
            *(uint4*)(s_b + row * 64 + pos * 8) = v;
        }
        __syncthreads();
        #pragma unroll
        for (int ks = 0; ks < 2; ++ks) {
            int g = ks * 4 + q;
            bf16x8 af[2], bfr[8];
            #pragma unroll
            for (int rt = 0; rt < 2; ++rt) {
                int row = w * 32 + rt * 16 + c0;
                af[rt] = *(const bf16x8*)(s_a + row * 64 + (g ^ (row & 7)) * 8);
            }
            #pragma unroll
            for (int ct = 0; ct < 8; ++ct) {
                int row = ct * 16 + c0;
                bfr[ct] = *(const bf16x8*)(s_b + row * 64 + (g ^ (row & 7)) * 8);
            }
            #pragma unroll
            for (int rt = 0; rt < 2; ++rt)
                #pragma unroll
                for (int ct = 0; ct < 8; ++ct)
                    acc[rt][ct] = __builtin_amdgcn_mfma_f32_16x16x32_bf16(
                        af[rt], bfr[ct], acc[rt][ct], 0, 0, 0);
        }
    }

    // epilogue: C layout col = ct*16 + c0, row-in-tile = q*4 + reg
    #pragma unroll
    for (int rt = 0; rt < 2; ++rt) {
        #pragma unroll
        for (int reg = 0; reg < 4; ++reg) {
            int nd = n0 + w * 32 + rt * 16 + q * 4 + reg;
            if (nd >= N_NODES) continue;
            float o[8];
            float s = 0.f;
            #pragma unroll
            for (int ct = 0; ct < 8; ++ct) {
                int col = ct * 16 + c0;
                float v = acc[rt][ct][reg] + s_bl[col] + bf2f(hres[(size_t)nd * HID + col]);
                v = fmaxf(v, 0.f);
                o[ct] = v;
                s += v;
                if (mode == 1) h[(size_t)nd * HID + col] = f2bf(v);
            }
            if (mode == 1) {
                #pragma unroll
                for (int off = 1; off < 16; off <<= 1) s += __shfl_xor(s, off, 64);
                float mu = s * (1.0f / HID);
                float qs = 0.f;
                #pragma unroll
                for (int ct = 0; ct < 8; ++ct) { float d = o[ct] - mu; qs += d * d; }
                #pragma unroll
                for (int off = 1; off < 16; off <<= 1) qs += __shfl_xor(qs, off, 64);
                float rstd = rsqrtf(qs * (1.0f / HID) + LN_EPS);
                #pragma unroll
                for (int ct = 0; ct < 8; ++ct) {
                    int col = ct * 16 + c0;
                    float hv = (o[ct] - mu) * rstd * s_g[col] + s_bb[col];
                    hnb[(size_t)nd * 128 + col] = f2bf(hv);
                    int r8 = __builtin_amdgcn_cvt_pk_fp8_f32(hv, hv, 0, false);
                    a8[(size_t)nd * 256 + 128 + col] = (unsigned char)(r8 & 0xff);
                }
            } else {
                float od0 = 0.f, od1 = 0.f, od2 = 0.f, od3 = 0.f;
                #pragma unroll
                for (int ct = 0; ct < 8; ++ct) {
                    int col = ct * 16 + c0;
                    float v = o[ct];
                    od0 += v * s_wo[col * 4 + 0];
                    od1 += v * s_wo[col * 4 + 1];
                    od2 += v * s_wo[col * 4 + 2];
                    od3 += v * s_wo[col * 4 + 3];
                }
                #pragma unroll
                for (int off = 1; off < 16; off <<= 1) {
                    od0 += __shfl_xor(od0, off, 64);
                    od1 += __shfl_xor(od1, off, 64);
                    od2 += __shfl_xor(od2, off, 64);
                    od3 += __shfl_xor(od3, off, 64);
                }
                if (c0 == 0) {
                    float4 r;
                    r.x = od0 + s_bo[0]; r.y = od1 + s_bo[1];
                    r.z = od2 + s_bo[2]; r.w = od3 + s_bo[3];
                    *(float4*)(out + (size_t)nd * D_OUT) = r;
                }
            }
        }
    }
}

extern "C" void kernel_launch(void* const* d_in, const int* in_sizes, int n_in,
                              void* d_out, int out_size, void* d_ws, size_t ws_size,
                              hipStream_t stream) {
    const float* x    = (const float*)d_in[0];
    const int*   ei   = (const int*)d_in[1];
    const float* W_in = (const float*)d_in[2];
    const float* b_in = (const float*)d_in[3];
    const float* Wl   = (const float*)d_in[4];
    const float* bl   = (const float*)d_in[5];
    const float* Wr   = (const float*)d_in[6];
    const float* ln_g = (const float*)d_in[7];
    const float* ln_b = (const float*)d_in[8];
    const float* W_out= (const float*)d_in[9];
    const float* b_out= (const float*)d_in[10];
    float* out = (float*)d_out;

    unsigned short* h   = (unsigned short*)d_ws;                 // [N][128] bf16
    unsigned short* hnb = h + (size_t)N_NODES * HID;             // [N][128] bf16
    unsigned short* BT  = hnb + (size_t)N_NODES * HID;           // 3*128*256 bf16
    unsigned char* a8   = (unsigned char*)(BT + (size_t)N_LAYERS * 128 * 256); // [N][256] fp8
    unsigned short* ell = (unsigned short*)(a8 + (size_t)N_NODES * 256); // N*48 ushort
    int*   cursor = (int*)(ell + (size_t)N_NODES * ELL_CAP);     // N ints
    int*   histM  = cursor + N_NODES;                            // 3125*196 ints
    int*   btotal = histM + (size_t)NBLK_E * NBUCK;              // 196 ints
    unsigned int* part = (unsigned int*)(btotal + 256);          // 196*5120 uints

    const int* src = ei;
    const int* dst = ei + N_EDGES;

    prep_kernel<<<NBLK_E + NB_W + NB_IN, 256, 0, stream>>>(
        dst, histM, Wl, Wr, BT, x, W_in, b_in, ln_g, ln_b, h, hnb, a8);
    scan_kernel<<<NBUCK, 256, 0, stream>>>(histM, btotal);
    scat_kernel<<<NBLK_E, 256, 0, stream>>>(src, dst, histM, part);
    ell_kernel<<<NBUCK, 256, 0, stream>>>(part, btotal, ell, cursor);

    for (int i = 0; i < N_LAYERS; ++i) {
        gather_kernel<<<(N_NODES + 15) / 16, 256, 0, stream>>>(cursor, ell, a8);
        int mode = (i + 1 < N_LAYERS) ? 1 : 2;
        const float* g_next = ln_g + (mode == 1 ? (size_t)(i + 1) * HID : 0);
        const float* b_next = ln_b + (mode == 1 ? (size_t)(i + 1) * HID : 0);
        conv_mfma_kernel<<<(N_NODES + 127) / 128, 256, 0, stream>>>(
            h, a8, a8, hnb, BT + (size_t)i * 128 * 256, bl + i * HID,
            g_next, b_next, h, W_out, b_out, out, mode);
    }
}

// Round 16
// 264.448 us; speedup vs baseline: 1.3209x; 1.0854x over previous
//
#include <hip/hip_runtime.h>

#define N_NODES 50000
#define N_EDGES 800000
#define D_IN 16
#define HID 128
#define D_OUT 4
#define N_LAYERS 3
#define LN_EPS 1e-5f
#define ELL_CAP 48
#define NBUCK 196                             // dst >> 8 buckets
#define BCAP 5120                             // bucket region capacity
#define SENT N_NODES                          // sentinel node id (zero row)
#define NBP 256                               // partition blocks
#define EPB (N_EDGES / NBP)                   // 3125 edges per partition block, exact
#define NB_W    (N_LAYERS * 128)              // 384
#define NB_IN   ((N_NODES + 3) / 4)           // 12500

typedef __attribute__((ext_vector_type(8))) short bf16x8;
typedef __attribute__((ext_vector_type(4))) float f32x4;
typedef __attribute__((ext_vector_type(2))) float f32x2;

__device__ __forceinline__ unsigned short f2bf(float f) {
    union { float f; unsigned int u; } a; a.f = f;
    unsigned int r = a.u + 0x7fffu + ((a.u >> 16) & 1u);   // RNE
    return (unsigned short)(r >> 16);
}
__device__ __forceinline__ unsigned int pack2(float x, float y) {
    return (unsigned int)f2bf(x) | ((unsigned int)f2bf(y) << 16);
}
__device__ __forceinline__ float bf2f(unsigned short u) {
    union { unsigned int u; float f; } c; c.u = (unsigned int)u << 16; return c.f;
}

// ---- prep: edge partition (LDS hist + chunk reservation) + wprep + in_proj/LN ----
__global__ __launch_bounds__(256) void prep_kernel(
        const int* __restrict__ src, const int* __restrict__ dst,
        int* __restrict__ gbase, unsigned int* __restrict__ part,
        const float* __restrict__ Wl, const float* __restrict__ Wr,
        unsigned short* __restrict__ BT,
        const float* __restrict__ x, const float* __restrict__ W_in,
        const float* __restrict__ b_in,
        const float* __restrict__ g0, const float* __restrict__ bb0,
        unsigned short* __restrict__ h, unsigned short* __restrict__ hnb,
        unsigned char* __restrict__ a8) {
    __shared__ int cnt[NBUCK];
    int b = blockIdx.x, t = threadIdx.x;
    if (b < NBP) {                            // edge partition
        if (t < NBUCK) cnt[t] = 0;
        __syncthreads();
        int e0 = b * EPB;
        for (int i = t; i < EPB; i += 256)
            atomicAdd(&cnt[dst[e0 + i] >> 8], 1);
        __syncthreads();
        int mybase = 0;
        if (t < NBUCK) mybase = atomicAdd(&gbase[t], cnt[t]);  // 196 atomics/block
        __syncthreads();
        if (t < NBUCK) cnt[t] = mybase;       // reuse as cursor
        __syncthreads();
        for (int i = t; i < EPB; i += 256) {
            int d = dst[e0 + i];
            int bk = d >> 8;
            int pos = atomicAdd(&cnt[bk], 1); // LDS atomic
            if (pos < BCAP)
                part[(size_t)bk * BCAP + pos] =
                    (unsigned int)src[e0 + i] | ((unsigned int)(d & 255) << 16);
        }
        return;
    }
    b -= NBP;
    if (b < NB_W) {                           // BT[i][n][k]
        int i = b >> 7, n = b & 127;
        float v = (t < 128) ? Wl[((size_t)i * 128 + t) * 128 + n]
                            : Wr[((size_t)i * 128 + (t - 128)) * 128 + n];
        BT[((size_t)i * 128 + n) * 256 + t] = f2bf(v);
        return;
    }
    b -= NB_W;                                // in_proj + first LN
    int wave = t >> 6, lane = t & 63;
    int node = b * 4 + wave;
    if (node >= N_NODES) return;
    int j0 = lane * 2;
    float a0 = b_in[j0], a1 = b_in[j0 + 1];
    const float* xr = x + (size_t)node * D_IN;
    #pragma unroll
    for (int k = 0; k < D_IN; ++k) {
        float xv = xr[k];
        float2 w = *(const float2*)(W_in + k * HID + j0);
        a0 += xv * w.x;
        a1 += xv * w.y;
    }
    ((unsigned int*)h)[(size_t)node * 64 + lane] = pack2(a0, a1);   // residual, bf16
    float s = a0 + a1;
    #pragma unroll
    for (int o = 32; o > 0; o >>= 1) s += __shfl_xor(s, o, 64);
    float mu = s * (1.0f / HID);
    float d0 = a0 - mu, d1 = a1 - mu;
    float q = d0 * d0 + d1 * d1;
    #pragma unroll
    for (int o = 32; o > 0; o >>= 1) q += __shfl_xor(q, o, 64);
    float rstd = rsqrtf(q * (1.0f / HID) + LN_EPS);
    float2 gg = *(const float2*)(g0 + j0);
    float2 bb = *(const float2*)(bb0 + j0);
    float h0 = d0 * rstd * gg.x + bb.x;
    float h1 = d1 * rstd * gg.y + bb.y;
    ((unsigned int*)hnb)[(size_t)node * 64 + lane] = pack2(h0, h1);  // bf16 (GEMM)
    int r8 = __builtin_amdgcn_cvt_pk_fp8_f32(h0, h1, 0, false);
    *(unsigned short*)(a8 + (size_t)node * 256 + 128 + j0) = (unsigned short)(r8 & 0xffff);
}

// ---- ELL build per bucket (LDS slot counters), pad rows to x8 with sentinel ----
__global__ __launch_bounds__(256) void ell_kernel(
        const unsigned int* __restrict__ part, const int* __restrict__ gbase,
        unsigned short* __restrict__ ell, int* __restrict__ cursor,
        unsigned char* __restrict__ a8) {
    __shared__ int cnt[256];
    int b = blockIdx.x, t = threadIdx.x;
    cnt[t] = 0;
    __syncthreads();
    int total = gbase[b];
    if (total > BCAP) total = BCAP;
    int n0 = b * 256;
    for (int i = t; i < total; i += 256) {
        unsigned int rec = part[(size_t)b * BCAP + i];
        int dl = rec >> 16;
        int slot = atomicAdd(&cnt[dl], 1);    // LDS atomic
        if (slot < ELL_CAP)
            ell[(size_t)(n0 + dl) * ELL_CAP + slot] = (unsigned short)(rec & 0xffff);
    }
    __syncthreads();
    int n = n0 + t;
    if (n < N_NODES) {
        int c = cnt[t];
        cursor[n] = c;
        int cap = c < ELL_CAP ? c : ELL_CAP;
        int padto = (cap + 7) & ~7;
        for (int s2 = cap; s2 < padto; ++s2)
            ell[(size_t)n * ELL_CAP + s2] = (unsigned short)SENT;
    }
    if (b == 0 && t < 32)                     // zero sentinel hn8 row
        ((unsigned int*)(a8 + (size_t)SENT * 256 + 128))[t] = 0u;
}

// ---- agg8 half of a8[n] = fp8( mean hn_fp8[src] ), rows padded to x8:
//      quarter-wave per node, uint2 fp8 loads, pure 8-deep MLP loop ----
__global__ __launch_bounds__(256) void gather_kernel(
        const int* __restrict__ cursor, const unsigned short* __restrict__ ell,
        unsigned char* __restrict__ a8) {
    int tid = threadIdx.x;
    int node = blockIdx.x * 16 + (tid >> 4);
    if (node >= N_NODES) return;
    int l = tid & 15;
    int qbase = (tid & 63) & ~15;
    const uint2* base = (const uint2*)a8;       // node stride = 32 uint2; hn half at +16
    const unsigned short* row = ell + (size_t)node * ELL_CAP;
    int cnt = cursor[node];
    int mc = cnt < ELL_CAP ? cnt : ELL_CAP;
    int mp = (mc + 7) & ~7;                     // padded with SENT (zero row)
    float a[8];
    #pragma unroll
    for (int j = 0; j < 8; ++j) a[j] = 0.f;
    for (int i = 0; i < mp; i += 8) {
        int sv = row[i + (l & 7)];              // lane qbase+j holds row[i + (j&7)]
        uint2 vv[8];
        #pragma unroll
        for (int j = 0; j < 8; ++j) {
            int s = __shfl(sv, qbase + j, 64);
            vv[j] = base[(size_t)s * 32 + 16 + l];
        }
        #pragma unroll
        for (int j = 0; j < 8; ++j) {
            f32x2 p0 = __builtin_amdgcn_cvt_pk_f32_fp8((int)vv[j].x, false);
            f32x2 p1 = __builtin_amdgcn_cvt_pk_f32_fp8((int)vv[j].x, true);
            f32x2 p2 = __builtin_amdgcn_cvt_pk_f32_fp8((int)vv[j].y, false);
            f32x2 p3 = __builtin_amdgcn_cvt_pk_f32_fp8((int)vv[j].y, true);
            a[0] += p0.x; a[1] += p0.y; a[2] += p1.x; a[3] += p1.y;
            a[4] += p2.x; a[5] += p2.y; a[6] += p3.x; a[7] += p3.y;
        }
    }
    float inv = 1.0f / fmaxf((float)cnt, 1.0f);
    int r0 = __builtin_amdgcn_cvt_pk_fp8_f32(a[0] * inv, a[1] * inv, 0, false);
    r0     = __builtin_amdgcn_cvt_pk_fp8_f32(a[2] * inv, a[3] * inv, r0, true);
    int r1 = __builtin_amdgcn_cvt_pk_fp8_f32(a[4] * inv, a[5] * inv, 0, false);
    r1     = __builtin_amdgcn_cvt_pk_fp8_f32(a[6] * inv, a[7] * inv, r1, true);
    uint2 o; o.x = (unsigned int)r0; o.y = (unsigned int)r1;
    ((uint2*)a8)[(size_t)node * 32 + l] = o;    // agg8 half (bytes 8l..8l+7)
}

// ---- conv: A = [agg8(fp8) | hnb(bf16)] 128x256; D = A @ BT^T; relu(hres+D+bl)
//      mode 1: write h(bf16) + next-LN -> hnb(bf16) + a8 hn-half(fp8)
//      mode 2: fused out-projection ----
__global__ __launch_bounds__(256) void conv_mfma_kernel(
        const unsigned short* __restrict__ hres, const unsigned char* __restrict__ a8c,
        unsigned char* __restrict__ a8, unsigned short* __restrict__ hnb,
        const unsigned short* __restrict__ BT, const float* __restrict__ bl,
        const float* __restrict__ lng, const float* __restrict__ lnb,
        unsigned short* __restrict__ h,
        const float* __restrict__ Wout, const float* __restrict__ bout,
        float* __restrict__ out, int mode) {
    __shared__ unsigned short s_a[128 * 64];   // 16 KB, XOR-swizzled 16B groups
    __shared__ unsigned short s_b[128 * 64];   // 16 KB
    __shared__ float s_bl[128], s_g[128], s_bb[128];
    __shared__ float s_wo[512];
    __shared__ float s_bo[4];
    int tid = threadIdx.x;
    int n0 = blockIdx.x * 128;
    if (tid < 128) {
        s_bl[tid] = bl[tid];
        s_g[tid]  = (mode == 1) ? lng[tid] : 0.f;
        s_bb[tid] = (mode == 1) ? lnb[tid] : 0.f;
    }
    if (mode == 2) {
        s_wo[tid]       = Wout[tid];
        s_wo[tid + 256] = Wout[tid + 256];
        if (tid < 4) s_bo[tid] = bout[tid];
    }
    int w = tid >> 6, lane = tid & 63;
    int q = lane >> 4, c0 = lane & 15;

    f32x4 acc[2][8];
    #pragma unroll
    for (int rt = 0; rt < 2; ++rt)
        #pragma unroll
        for (int ct = 0; ct < 8; ++ct) acc[rt][ct] = (f32x4){0.f, 0.f, 0.f, 0.f};

    for (int kc = 0; kc < 4; ++kc) {
        if (kc) __syncthreads();
        if (kc < 2) {                      // stage A from agg8 (fp8 -> bf16)
            #pragma unroll
            for (int p = 0; p < 2; ++p) {
                int f = p * 256 + tid;
                int row = f >> 2, j = f & 3;
                uint4 v = {0u, 0u, 0u, 0u};
                int node = n0 + row;
                if (node < N_NODES)
                    v = *(const uint4*)(a8c + (size_t)node * 256 + kc * 64 + j * 16);
                f32x2 p0 = __builtin_amdgcn_cvt_pk_f32_fp8((int)v.x, false);
                f32x2 p1 = __builtin_amdgcn_cvt_pk_f32_fp8((int)v.x, true);
                f32x2 p2 = __builtin_amdgcn_cvt_pk_f32_fp8((int)v.y, false);
                f32x2 p3 = __builtin_amdgcn_cvt_pk_f32_fp8((int)v.y, true);
                uint4 o0;
                o0.x = pack2(p0.x, p0.y); o0.y = pack2(p1.x, p1.y);
                o0.z = pack2(p2.x, p2.y); o0.w = pack2(p3.x, p3.y);
                p0 = __builtin_amdgcn_cvt_pk_f32_fp8((int)v.z, false);
                p1 = __builtin_amdgcn_cvt_pk_f32_fp8((int)v.z, true);
                p2 = __builtin_amdgcn_cvt_pk_f32_fp8((int)v.w, false);
                p3 = __builtin_amdgcn_cvt_pk_f32_fp8((int)v.w, true);
                uint4 o1;
                o1.x = pack2(p0.x, p0.y); o1.y = pack2(p1.x, p1.y);
                o1.z = pack2(p2.x, p2.y); o1.w = pack2(p3.x, p3.y);
                int g0 = 2 * j, g1 = 2 * j + 1;
                *(uint4*)(s_a + row * 64 + (g0 ^ (row & 7)) * 8) = o0;
                *(uint4*)(s_a + row * 64 + (g1 ^ (row & 7)) * 8) = o1;
            }
        } else {                           // stage A from hnb (bf16 direct)
            #pragma unroll
            for (int p = 0; p < 4; ++p) {
                int f = p * 256 + tid;
                int row = f >> 3, g = f & 7;
                int pos = g ^ (row & 7);
                uint4 v = {0u, 0u, 0u, 0u};
                int node = n0 + row;
                if (node < N_NODES)
                    v = *(const uint4*)(hnb + (size_t)node * 128 + (kc - 2) * 64 + g * 8);
                *(uint4*)(s_a + row * 64 + pos * 8) = v;
            }
        }
        #pragma unroll
        for (int p = 0; p < 4; ++p) {      // stage B chunk
            int f = p * 256 + tid;
            int row = f >> 3, g = f & 7;
            int pos = g ^ (row & 7);
            uint4 v = *(const uint4*)(BT + (size_t)row * 256 + kc * 64 + g * 8);
            *(uint4*)(s_b + row * 64 + pos * 8) = v;
        }
        __syncthreads();
        #pragma unroll
        for (int ks = 0; ks < 2; ++ks) {
            int g = ks * 4 + q;
            bf16x8 af[2], bfr[8];
            #pragma unroll
            for (int rt = 0; rt < 2; ++rt) {
                int row = w * 32 + rt * 16 + c0;
                af[rt] = *(const bf16x8*)(s_a + row * 64 + (g ^ (row & 7)) * 8);
            }
            #pragma unroll
            for (int ct = 0; ct < 8; ++ct) {
                int row = ct * 16 + c0;
                bfr[ct] = *(const bf16x8*)(s_b + row * 64 + (g ^ (row & 7)) * 8);
            }
            #pragma unroll
            for (int rt = 0; rt < 2; ++rt)
                #pragma unroll
                for (int ct = 0; ct < 8; ++ct)
                    acc[rt][ct] = __builtin_amdgcn_mfma_f32_16x16x32_bf16(
                        af[rt], bfr[ct], acc[rt][ct], 0, 0, 0);
        }
    }

    // epilogue: C layout col = ct*16 + c0, row-in-tile = q*4 + reg
    #pragma unroll
    for (int rt = 0; rt < 2; ++rt) {
        #pragma unroll
        for (int reg = 0; reg < 4; ++reg) {
            int nd = n0 + w * 32 + rt * 16 + q * 4 + reg;
            if (nd >= N_NODES) continue;
            float o[8];
            float s = 0.f;
            #pragma unroll
            for (int ct = 0; ct < 8; ++ct) {
                int col = ct * 16 + c0;
                float v = acc[rt][ct][reg] + s_bl[col] + bf2f(hres[(size_t)nd * HID + col]);
                v = fmaxf(v, 0.f);
                o[ct] = v;
                s += v;
                if (mode == 1) h[(size_t)nd * HID + col] = f2bf(v);
            }
            if (mode == 1) {
                #pragma unroll
                for (int off = 1; off < 16; off <<= 1) s += __shfl_xor(s, off, 64);
                float mu = s * (1.0f / HID);
                float qs = 0.f;
                #pragma unroll
                for (int ct = 0; ct < 8; ++ct) { float d = o[ct] - mu; qs += d * d; }
                #pragma unroll
                for (int off = 1; off < 16; off <<= 1) qs += __shfl_xor(qs, off, 64);
                float rstd = rsqrtf(qs * (1.0f / HID) + LN_EPS);
                #pragma unroll
                for (int ct = 0; ct < 8; ++ct) {
                    int col = ct * 16 + c0;
                    float hv = (o[ct] - mu) * rstd * s_g[col] + s_bb[col];
                    hnb[(size_t)nd * 128 + col] = f2bf(hv);
                    int r8 = __builtin_amdgcn_cvt_pk_fp8_f32(hv, hv, 0, false);
                    a8[(size_t)nd * 256 + 128 + col] = (unsigned char)(r8 & 0xff);
                }
            } else {
                float od0 = 0.f, od1 = 0.f, od2 = 0.f, od3 = 0.f;
                #pragma unroll
                for (int ct = 0; ct < 8; ++ct) {
                    int col = ct * 16 + c0;
                    float v = o[ct];
                    od0 += v * s_wo[col * 4 + 0];
                    od1 += v * s_wo[col * 4 + 1];
                    od2 += v * s_wo[col * 4 + 2];
                    od3 += v * s_wo[col * 4 + 3];
                }
                #pragma unroll
                for (int off = 1; off < 16; off <<= 1) {
                    od0 += __shfl_xor(od0, off, 64);
                    od1 += __shfl_xor(od1, off, 64);
                    od2 += __shfl_xor(od2, off, 64);
                    od3 += __shfl_xor(od3, off, 64);
                }
                if (c0 == 0) {
                    float4 r;
                    r.x = od0 + s_bo[0]; r.y = od1 + s_bo[1];
                    r.z = od2 + s_bo[2]; r.w = od3 + s_bo[3];
                    *(float4*)(out + (size_t)nd * D_OUT) = r;
                }
            }
        }
    }
}

extern "C" void kernel_launch(void* const* d_in, const int* in_sizes, int n_in,
                              void* d_out, int out_size, void* d_ws, size_t ws_size,
                              hipStream_t stream) {
    const float* x    = (const float*)d_in[0];
    const int*   ei   = (const int*)d_in[1];
    const float* W_in = (const float*)d_in[2];
    const float* b_in = (const float*)d_in[3];
    const float* Wl   = (const float*)d_in[4];
    const float* bl   = (const float*)d_in[5];
    const float* Wr   = (const float*)d_in[6];
    const float* ln_g = (const float*)d_in[7];
    const float* ln_b = (const float*)d_in[8];
    const float* W_out= (const float*)d_in[9];
    const float* b_out= (const float*)d_in[10];
    float* out = (float*)d_out;

    unsigned short* h   = (unsigned short*)d_ws;                 // [N][128] bf16
    unsigned short* hnb = h + (size_t)N_NODES * HID;             // [N][128] bf16
    unsigned short* BT  = hnb + (size_t)N_NODES * HID;           // 3*128*256 bf16
    unsigned char* a8   = (unsigned char*)(BT + (size_t)N_LAYERS * 128 * 256); // [N+1][256] fp8
    unsigned short* ell = (unsigned short*)(a8 + (size_t)(N_NODES + 1) * 256); // N*48 ushort
    int*   cursor = (int*)(ell + (size_t)N_NODES * ELL_CAP);     // N ints
    int*   gbase  = cursor + N_NODES;                            // 256 ints (memset)
    unsigned int* part = (unsigned int*)(gbase + 256);           // 196*5120 uints

    const int* src = ei;
    const int* dst = ei + N_EDGES;

    hipMemsetAsync(gbase, 0, 256 * sizeof(int), stream);

    prep_kernel<<<NBP + NB_W + NB_IN, 256, 0, stream>>>(
        src, dst, gbase, part, Wl, Wr, BT, x, W_in, b_in, ln_g, ln_b, h, hnb, a8);
    ell_kernel<<<NBUCK, 256, 0, stream>>>(part, gbase, ell, cursor, a8);

    for (int i = 0; i < N_LAYERS; ++i) {
        gather_kernel<<<(N_NODES + 15) / 16, 256, 0, stream>>>(cursor, ell, a8);
        int mode = (i + 1 < N_LAYERS) ? 1 : 2;
        const float* g_next = ln_g + (mode == 1 ? (size_t)(i + 1) * HID : 0);
        const float* b_next = ln_b + (mode == 1 ? (size_t)(i + 1) * HID : 0);
        conv_mfma_kernel<<<(N_NODES + 127) / 128, 256, 0, stream>>>(
            h, a8, a8, hnb, BT + (size_t)i * 128 * 256, bl + i * HID,
            g_next, b_next, h, W_out, b_out, out, mode);
    }
}

// Round 17
// 229.241 us; speedup vs baseline: 1.5238x; 1.1536x over previous
//
#include <hip/hip_runtime.h>

#define N_NODES 50000
#define N_EDGES 800000
#define D_IN 16
#define HID 128
#define D_OUT 4
#define N_LAYERS 3
#define LN_EPS 1e-5f
#define ELL_CAP 48
#define NBUCK 196                             // dst >> 8 buckets
#define BCAP 5120                             // bucket region capacity
#define SENT N_NODES                          // sentinel node id (zero row)
#define NBP 256                               // partition blocks
#define EPB (N_EDGES / NBP)                   // 3125 edges per partition block, exact
#define NB_W    (N_LAYERS * 128)              // 384
#define NB_IN   (N_NODES / 16)                // 3125, exact

typedef __attribute__((ext_vector_type(8))) short bf16x8;
typedef __attribute__((ext_vector_type(4))) float f32x4;
typedef __attribute__((ext_vector_type(2))) float f32x2;

__device__ __forceinline__ unsigned short f2bf(float f) {
    union { float f; unsigned int u; } a; a.f = f;
    unsigned int r = a.u + 0x7fffu + ((a.u >> 16) & 1u);   // RNE
    return (unsigned short)(r >> 16);
}
__device__ __forceinline__ unsigned int pack2(float x, float y) {
    return (unsigned int)f2bf(x) | ((unsigned int)f2bf(y) << 16);
}
__device__ __forceinline__ float bf2f(unsigned short u) {
    union { unsigned int u; float f; } c; c.u = (unsigned int)u << 16; return c.f;
}

// ---- prep: edge partition + wprep + in_proj/LN (16 nodes/block) ----
__global__ __launch_bounds__(256) void prep_kernel(
        const int* __restrict__ src, const int* __restrict__ dst,
        int* __restrict__ gbase, unsigned int* __restrict__ part,
        const float* __restrict__ Wl, const float* __restrict__ Wr,
        unsigned short* __restrict__ BT,
        const float* __restrict__ x, const float* __restrict__ W_in,
        const float* __restrict__ b_in,
        const float* __restrict__ g0, const float* __restrict__ bb0,
        unsigned short* __restrict__ h, unsigned short* __restrict__ hnb,
        unsigned char* __restrict__ a8) {
    __shared__ int cnt[NBUCK];
    int b = blockIdx.x, t = threadIdx.x;
    if (b < NBP) {                            // edge partition
        if (t < NBUCK) cnt[t] = 0;
        __syncthreads();
        int e0 = b * EPB;
        for (int i = t; i < EPB; i += 256)
            atomicAdd(&cnt[dst[e0 + i] >> 8], 1);
        __syncthreads();
        int mybase = 0;
        if (t < NBUCK) mybase = atomicAdd(&gbase[t], cnt[t]);  // 196 atomics/block
        __syncthreads();
        if (t < NBUCK) cnt[t] = mybase;       // reuse as cursor
        __syncthreads();
        for (int i = t; i < EPB; i += 256) {
            int d = dst[e0 + i];
            int bk = d >> 8;
            int pos = atomicAdd(&cnt[bk], 1); // LDS atomic
            if (pos < BCAP)
                part[(size_t)bk * BCAP + pos] =
                    (unsigned int)src[e0 + i] | ((unsigned int)(d & 255) << 16);
        }
        return;
    }
    b -= NBP;
    if (b < NB_W) {                           // BT[i][n][k]
        int i = b >> 7, n = b & 127;
        float v = (t < 128) ? Wl[((size_t)i * 128 + t) * 128 + n]
                            : Wr[((size_t)i * 128 + (t - 128)) * 128 + n];
        BT[((size_t)i * 128 + n) * 256 + t] = f2bf(v);
        return;
    }
    b -= NB_W;                                // in_proj + first LN: quarter-wave/node
    int l = t & 15, nq = t >> 4;
    int node = b * 16 + nq;                   // 3125*16 = 50000 exact
    if (node >= N_NODES) return;
    int qb = (t & 63) & ~15;
    int j0 = l * 8;
    float xv = x[(size_t)node * D_IN + l];    // lane l holds x_k, k=l (coalesced)
    float acc[8];
    {
        float4 b0 = *(const float4*)(b_in + j0);
        float4 b1 = *(const float4*)(b_in + j0 + 4);
        acc[0] = b0.x; acc[1] = b0.y; acc[2] = b0.z; acc[3] = b0.w;
        acc[4] = b1.x; acc[5] = b1.y; acc[6] = b1.z; acc[7] = b1.w;
    }
    #pragma unroll
    for (int k = 0; k < D_IN; ++k) {
        float xk = __shfl(xv, qb + k, 64);
        float4 w0 = *(const float4*)(W_in + k * HID + j0);
        float4 w1 = *(const float4*)(W_in + k * HID + j0 + 4);
        acc[0] += xk * w0.x; acc[1] += xk * w0.y; acc[2] += xk * w0.z; acc[3] += xk * w0.w;
        acc[4] += xk * w1.x; acc[5] += xk * w1.y; acc[6] += xk * w1.z; acc[7] += xk * w1.w;
    }
    unsigned int hw[4];
    hw[0] = pack2(acc[0], acc[1]); hw[1] = pack2(acc[2], acc[3]);
    hw[2] = pack2(acc[4], acc[5]); hw[3] = pack2(acc[6], acc[7]);
    ((uint4*)h)[(size_t)node * 16 + l] = *(uint4*)hw;     // residual, bf16
    float s = ((acc[0] + acc[1]) + (acc[2] + acc[3])) + ((acc[4] + acc[5]) + (acc[6] + acc[7]));
    #pragma unroll
    for (int o = 1; o < 16; o <<= 1) s += __shfl_xor(s, o, 64);
    float mu = s * (1.0f / HID);
    float qs = 0.f;
    float d[8];
    #pragma unroll
    for (int j = 0; j < 8; ++j) { d[j] = acc[j] - mu; qs += d[j] * d[j]; }
    #pragma unroll
    for (int o = 1; o < 16; o <<= 1) qs += __shfl_xor(qs, o, 64);
    float rstd = rsqrtf(qs * (1.0f / HID) + LN_EPS);
    float4 gv0 = *(const float4*)(g0 + j0), gv1 = *(const float4*)(g0 + j0 + 4);
    float4 bv0 = *(const float4*)(bb0 + j0), bv1 = *(const float4*)(bb0 + j0 + 4);
    float hv[8];
    hv[0] = d[0] * rstd * gv0.x + bv0.x; hv[1] = d[1] * rstd * gv0.y + bv0.y;
    hv[2] = d[2] * rstd * gv0.z + bv0.z; hv[3] = d[3] * rstd * gv0.w + bv0.w;
    hv[4] = d[4] * rstd * gv1.x + bv1.x; hv[5] = d[5] * rstd * gv1.y + bv1.y;
    hv[6] = d[6] * rstd * gv1.z + bv1.z; hv[7] = d[7] * rstd * gv1.w + bv1.w;
    unsigned int nw[4];
    nw[0] = pack2(hv[0], hv[1]); nw[1] = pack2(hv[2], hv[3]);
    nw[2] = pack2(hv[4], hv[5]); nw[3] = pack2(hv[6], hv[7]);
    ((uint4*)hnb)[(size_t)node * 16 + l] = *(uint4*)nw;   // bf16 (GEMM input)
    int r0 = __builtin_amdgcn_cvt_pk_fp8_f32(hv[0], hv[1], 0, false);
    r0     = __builtin_amdgcn_cvt_pk_fp8_f32(hv[2], hv[3], r0, true);
    int r1 = __builtin_amdgcn_cvt_pk_fp8_f32(hv[4], hv[5], 0, false);
    r1     = __builtin_amdgcn_cvt_pk_fp8_f32(hv[6], hv[7], r1, true);
    uint2 o8; o8.x = (unsigned int)r0; o8.y = (unsigned int)r1;
    *(uint2*)(a8 + (size_t)node * 256 + 128 + (size_t)l * 8) = o8;
}

// ---- ELL build per bucket (LDS slot counters), pad rows to x8 with sentinel ----
__global__ __launch_bounds__(256) void ell_kernel(
        const unsigned int* __restrict__ part, const int* __restrict__ gbase,
        unsigned short* __restrict__ ell, int* __restrict__ cursor,
        unsigned char* __restrict__ a8) {
    __shared__ int cnt[256];
    int b = blockIdx.x, t = threadIdx.x;
    cnt[t] = 0;
    __syncthreads();
    int total = gbase[b];
    if (total > BCAP) total = BCAP;
    int n0 = b * 256;
    for (int i = t; i < total; i += 256) {
        unsigned int rec = part[(size_t)b * BCAP + i];
        int dl = rec >> 16;
        int slot = atomicAdd(&cnt[dl], 1);    // LDS atomic
        if (slot < ELL_CAP)
            ell[(size_t)(n0 + dl) * ELL_CAP + slot] = (unsigned short)(rec & 0xffff);
    }
    __syncthreads();
    int n = n0 + t;
    if (n < N_NODES) {
        int c = cnt[t];
        cursor[n] = c;
        int cap = c < ELL_CAP ? c : ELL_CAP;
        int padto = (cap + 7) & ~7;
        for (int s2 = cap; s2 < padto; ++s2)
            ell[(size_t)n * ELL_CAP + s2] = (unsigned short)SENT;
    }
    if (b == 0 && t < 32)                     // zero sentinel hn8 row
        ((unsigned int*)(a8 + (size_t)SENT * 256 + 128))[t] = 0u;
}

// ---- agg8 half of a8[n] = fp8( mean hn_fp8[src] ), rows padded to x8 ----
__global__ __launch_bounds__(256) void gather_kernel(
        const int* __restrict__ cursor, const unsigned short* __restrict__ ell,
        unsigned char* __restrict__ a8) {
    int tid = threadIdx.x;
    int node = blockIdx.x * 16 + (tid >> 4);
    if (node >= N_NODES) return;
    int l = tid & 15;
    int qbase = (tid & 63) & ~15;
    const uint2* base = (const uint2*)a8;       // node stride = 32 uint2; hn half at +16
    const unsigned short* row = ell + (size_t)node * ELL_CAP;
    int cnt = cursor[node];
    int mc = cnt < ELL_CAP ? cnt : ELL_CAP;
    int mp = (mc + 7) & ~7;                     // padded with SENT (zero row)
    float a[8];
    #pragma unroll
    for (int j = 0; j < 8; ++j) a[j] = 0.f;
    for (int i = 0; i < mp; i += 8) {
        int sv = row[i + (l & 7)];
        uint2 vv[8];
        #pragma unroll
        for (int j = 0; j < 8; ++j) {
            int s = __shfl(sv, qbase + j, 64);
            vv[j] = base[(size_t)s * 32 + 16 + l];
        }
        #pragma unroll
        for (int j = 0; j < 8; ++j) {
            f32x2 p0 = __builtin_amdgcn_cvt_pk_f32_fp8((int)vv[j].x, false);
            f32x2 p1 = __builtin_amdgcn_cvt_pk_f32_fp8((int)vv[j].x, true);
            f32x2 p2 = __builtin_amdgcn_cvt_pk_f32_fp8((int)vv[j].y, false);
            f32x2 p3 = __builtin_amdgcn_cvt_pk_f32_fp8((int)vv[j].y, true);
            a[0] += p0.x; a[1] += p0.y; a[2] += p1.x; a[3] += p1.y;
            a[4] += p2.x; a[5] += p2.y; a[6] += p3.x; a[7] += p3.y;
        }
    }
    float inv = 1.0f / fmaxf((float)cnt, 1.0f);
    int r0 = __builtin_amdgcn_cvt_pk_fp8_f32(a[0] * inv, a[1] * inv, 0, false);
    r0     = __builtin_amdgcn_cvt_pk_fp8_f32(a[2] * inv, a[3] * inv, r0, true);
    int r1 = __builtin_amdgcn_cvt_pk_fp8_f32(a[4] * inv, a[5] * inv, 0, false);
    r1     = __builtin_amdgcn_cvt_pk_fp8_f32(a[6] * inv, a[7] * inv, r1, true);
    uint2 o; o.x = (unsigned int)r0; o.y = (unsigned int)r1;
    ((uint2*)a8)[(size_t)node * 32 + l] = o;    // agg8 half
}

// ---- conv: A = [agg8(fp8) | hnb(bf16)] 128x256; D = A @ BT^T; relu(hres+D+bl)
//      mode 1: LDS-staged coalesced flush of h, then LN -> hnb + a8 hn-half
//      mode 2: fused out-projection ----
__global__ __launch_bounds__(256) void conv_mfma_kernel(
        const unsigned short* __restrict__ hres, const unsigned char* __restrict__ a8c,
        unsigned char* __restrict__ a8, unsigned short* __restrict__ hnb,
        const unsigned short* __restrict__ BT, const float* __restrict__ bl,
        const float* __restrict__ lng, const float* __restrict__ lnb,
        unsigned short* __restrict__ h,
        const float* __restrict__ Wout, const float* __restrict__ bout,
        float* __restrict__ out, int mode) {
    __shared__ unsigned short s_ab[2 * 128 * 64];   // 32 KB: staging, then epilogue
    unsigned short* s_a = s_ab;
    unsigned short* s_b = s_ab + 128 * 64;
    __shared__ float s_bl[128], s_g[128], s_bb[128];
    __shared__ float s_wo[512];
    __shared__ float s_bo[4];
    int tid = threadIdx.x;
    int n0 = blockIdx.x * 128;
    if (tid < 128) {
        s_bl[tid] = bl[tid];
        s_g[tid]  = (mode == 1) ? lng[tid] : 0.f;
        s_bb[tid] = (mode == 1) ? lnb[tid] : 0.f;
    }
    if (mode == 2) {
        s_wo[tid]       = Wout[tid];
        s_wo[tid + 256] = Wout[tid + 256];
        if (tid < 4) s_bo[tid] = bout[tid];
    }
    int w = tid >> 6, lane = tid & 63;
    int q = lane >> 4, c0 = lane & 15;

    f32x4 acc[2][8];
    #pragma unroll
    for (int rt = 0; rt < 2; ++rt)
        #pragma unroll
        for (int ct = 0; ct < 8; ++ct) acc[rt][ct] = (f32x4){0.f, 0.f, 0.f, 0.f};

    for (int kc = 0; kc < 4; ++kc) {
        if (kc) __syncthreads();
        if (kc < 2) {                      // stage A from agg8 (fp8 -> bf16)
            #pragma unroll
            for (int p = 0; p < 2; ++p) {
                int f = p * 256 + tid;
                int row = f >> 2, j = f & 3;
                uint4 v = {0u, 0u, 0u, 0u};
                int node = n0 + row;
                if (node < N_NODES)
                    v = *(const uint4*)(a8c + (size_t)node * 256 + kc * 64 + j * 16);
                f32x2 p0 = __builtin_amdgcn_cvt_pk_f32_fp8((int)v.x, false);
                f32x2 p1 = __builtin_amdgcn_cvt_pk_f32_fp8((int)v.x, true);
                f32x2 p2 = __builtin_amdgcn_cvt_pk_f32_fp8((int)v.y, false);
                f32x2 p3 = __builtin_amdgcn_cvt_pk_f32_fp8((int)v.y, true);
                uint4 o0;
                o0.x = pack2(p0.x, p0.y); o0.y = pack2(p1.x, p1.y);
                o0.z = pack2(p2.x, p2.y); o0.w = pack2(p3.x, p3.y);
                p0 = __builtin_amdgcn_cvt_pk_f32_fp8((int)v.z, false);
                p1 = __builtin_amdgcn_cvt_pk_f32_fp8((int)v.z, true);
                p2 = __builtin_amdgcn_cvt_pk_f32_fp8((int)v.w, false);
                p3 = __builtin_amdgcn_cvt_pk_f32_fp8((int)v.w, true);
                uint4 o1;
                o1.x = pack2(p0.x, p0.y); o1.y = pack2(p1.x, p1.y);
                o1.z = pack2(p2.x, p2.y); o1.w = pack2(p3.x, p3.y);
                int g0 = 2 * j, g1 = 2 * j + 1;
                *(uint4*)(s_a + row * 64 + (g0 ^ (row & 7)) * 8) = o0;
                *(uint4*)(s_a + row * 64 + (g1 ^ (row & 7)) * 8) = o1;
            }
        } else {                           // stage A from hnb (bf16 direct)
            #pragma unroll
            for (int p = 0; p < 4; ++p) {
                int f = p * 256 + tid;
                int row = f >> 3, g = f & 7;
                int pos = g ^ (row & 7);
                uint4 v = {0u, 0u, 0u, 0u};
                int node = n0 + row;
                if (node < N_NODES)
                    v = *(const uint4*)(hnb + (size_t)node * 128 + (kc - 2) * 64 + g * 8);
                *(uint4*)(s_a + row * 64 + pos * 8) = v;
            }
        }
        #pragma unroll
        for (int p = 0; p < 4; ++p) {      // stage B chunk
            int f = p * 256 + tid;
            int row = f >> 3, g = f & 7;
            int pos = g ^ (row & 7);
            uint4 v = *(const uint4*)(BT + (size_t)row * 256 + kc * 64 + g * 8);
            *(uint4*)(s_b + row * 64 + pos * 8) = v;
        }
        __syncthreads();
        #pragma unroll
        for (int ks = 0; ks < 2; ++ks) {
            int g = ks * 4 + q;
            bf16x8 af[2], bfr[8];
            #pragma unroll
            for (int rt = 0; rt < 2; ++rt) {
                int row = w * 32 + rt * 16 + c0;
                af[rt] = *(const bf16x8*)(s_a + row * 64 + (g ^ (row & 7)) * 8);
            }
            #pragma unroll
            for (int ct = 0; ct < 8; ++ct) {
                int row = ct * 16 + c0;
                bfr[ct] = *(const bf16x8*)(s_b + row * 64 + (g ^ (row & 7)) * 8);
            }
            #pragma unroll
            for (int rt = 0; rt < 2; ++rt)
                #pragma unroll
                for (int ct = 0; ct < 8; ++ct)
                    acc[rt][ct] = __builtin_amdgcn_mfma_f32_16x16x32_bf16(
                        af[rt], bfr[ct], acc[rt][ct], 0, 0, 0);
        }
    }

    if (mode == 1) {
        __syncthreads();                       // all s_a/s_b reads done
        unsigned short* s_out = s_ab;          // 128 x 128 bf16
        // E1: h = relu(D + bl + hres) -> s_out
        #pragma unroll
        for (int rt = 0; rt < 2; ++rt)
        #pragma unroll
        for (int reg = 0; reg < 4; ++reg) {
            int row = w * 32 + rt * 16 + q * 4 + reg;
            int nd = n0 + row;
            if (nd >= N_NODES) continue;
            #pragma unroll
            for (int ct = 0; ct < 8; ++ct) {
                int col = ct * 16 + c0;
                float v = acc[rt][ct][reg] + s_bl[col] + bf2f(hres[(size_t)nd * HID + col]);
                s_out[row * 128 + col] = f2bf(fmaxf(v, 0.f));
            }
        }
        __syncthreads();
        {   // flush h: thread -> (row, half), 128 B contiguous
            int row = tid >> 1, half = tid & 1;
            if (n0 + row < N_NODES) {
                const uint4* sp = (const uint4*)s_ab + row * 16 + half * 8;
                uint4* gp = (uint4*)h + (size_t)(n0 + row) * 16 + half * 8;
                #pragma unroll
                for (int i = 0; i < 8; ++i) gp[i] = sp[i];
            }
        }
        __syncthreads();
        // LN in place on s_out
        #pragma unroll
        for (int rt = 0; rt < 2; ++rt)
        #pragma unroll
        for (int reg = 0; reg < 4; ++reg) {
            int row = w * 32 + rt * 16 + q * 4 + reg;
            int nd = n0 + row;
            if (nd >= N_NODES) continue;
            float o2[8]; float s = 0.f;
            #pragma unroll
            for (int ct = 0; ct < 8; ++ct) {
                o2[ct] = bf2f(s_out[row * 128 + ct * 16 + c0]);
                s += o2[ct];
            }
            #pragma unroll
            for (int off = 1; off < 16; off <<= 1) s += __shfl_xor(s, off, 64);
            float mu = s * (1.0f / HID);
            float qs = 0.f;
            #pragma unroll
            for (int ct = 0; ct < 8; ++ct) { float d = o2[ct] - mu; qs += d * d; }
            #pragma unroll
            for (int off = 1; off < 16; off <<= 1) qs += __shfl_xor(qs, off, 64);
            float rstd = rsqrtf(qs * (1.0f / HID) + LN_EPS);
            #pragma unroll
            for (int ct = 0; ct < 8; ++ct) {
                int col = ct * 16 + c0;
                float hv = (o2[ct] - mu) * rstd * s_g[col] + s_bb[col];
                s_out[row * 128 + col] = f2bf(hv);
            }
        }
        __syncthreads();
        {   // flush hnb + a8
            int row = tid >> 1, half = tid & 1;
            if (n0 + row < N_NODES) {
                const uint4* sp = (const uint4*)s_ab + row * 16 + half * 8;
                uint4* gp = (uint4*)hnb + (size_t)(n0 + row) * 16 + half * 8;
                uint4 vv[8];
                #pragma unroll
                for (int i = 0; i < 8; ++i) { vv[i] = sp[i]; gp[i] = vv[i]; }
                unsigned int w8[16];
                #pragma unroll
                for (int i = 0; i < 8; ++i) {
                    const unsigned int* pu = (const unsigned int*)&vv[i];
                    #pragma unroll
                    for (int k2 = 0; k2 < 2; ++k2) {
                        unsigned int u0 = pu[2 * k2], u1 = pu[2 * k2 + 1];
                        int r = __builtin_amdgcn_cvt_pk_fp8_f32(
                            bf2f((unsigned short)(u0 & 0xffff)),
                            bf2f((unsigned short)(u0 >> 16)), 0, false);
                        r = __builtin_amdgcn_cvt_pk_fp8_f32(
                            bf2f((unsigned short)(u1 & 0xffff)),
                            bf2f((unsigned short)(u1 >> 16)), r, true);
                        w8[i * 2 + k2] = (unsigned int)r;
                    }
                }
                uint4* ap = (uint4*)(a8 + (size_t)(n0 + row) * 256 + 128 + half * 64);
                #pragma unroll
                for (int i = 0; i < 4; ++i) ap[i] = *(uint4*)&w8[i * 4];
            }
        }
    } else {
        // mode 2: out-projection epilogue (registers only)
        #pragma unroll
        for (int rt = 0; rt < 2; ++rt) {
            #pragma unroll
            for (int reg = 0; reg < 4; ++reg) {
                int nd = n0 + w * 32 + rt * 16 + q * 4 + reg;
                if (nd >= N_NODES) continue;
                float od0 = 0.f, od1 = 0.f, od2 = 0.f, od3 = 0.f;
                #pragma unroll
                for (int ct = 0; ct < 8; ++ct) {
                    int col = ct * 16 + c0;
                    float v = acc[rt][ct][reg] + s_bl[col] + bf2f(hres[(size_t)nd * HID + col]);
                    v = fmaxf(v, 0.f);
                    od0 += v * s_wo[col * 4 + 0];
                    od1 += v * s_wo[col * 4 + 1];
                    od2 += v * s_wo[col * 4 + 2];
                    od3 += v * s_wo[col * 4 + 3];
                }
                #pragma unroll
                for (int off = 1; off < 16; off <<= 1) {
                    od0 += __shfl_xor(od0, off, 64);
                    od1 += __shfl_xor(od1, off, 64);
                    od2 += __shfl_xor(od2, off, 64);
                    od3 += __shfl_xor(od3, off, 64);
                }
                if (c0 == 0) {
                    float4 r;
                    r.x = od0 + s_bo[0]; r.y = od1 + s_bo[1];
                    r.z = od2 + s_bo[2]; r.w = od3 + s_bo[3];
                    *(float4*)(out + (size_t)nd * D_OUT) = r;
                }
            }
        }
    }
}

extern "C" void kernel_launch(void* const* d_in, const int* in_sizes, int n_in,
                              void* d_out, int out_size, void* d_ws, size_t ws_size,
                              hipStream_t stream) {
    const float* x    = (const float*)d_in[0];
    const int*   ei   = (const int*)d_in[1];
    const float* W_in = (const float*)d_in[2];
    const float* b_in = (const float*)d_in[3];
    const float* Wl   = (const float*)d_in[4];
    const float* bl   = (const float*)d_in[5];
    const float* Wr   = (const float*)d_in[6];
    const float* ln_g = (const float*)d_in[7];
    const float* ln_b = (const float*)d_in[8];
    const float* W_out= (const float*)d_in[9];
    const float* b_out= (const float*)d_in[10];
    float* out = (float*)d_out;

    unsigned short* h   = (unsigned short*)d_ws;                 // [N][128] bf16
    unsigned short* hnb = h + (size_t)N_NODES * HID;             // [N][128] bf16
    unsigned short* BT  = hnb + (size_t)N_NODES * HID;           // 3*128*256 bf16
    unsigned char* a8   = (unsigned char*)(BT + (size_t)N_LAYERS * 128 * 256); // [N+1][256] fp8
    unsigned short* ell = (unsigned short*)(a8 + (size_t)(N_NODES + 1) * 256); // N*48 ushort
    int*   cursor = (int*)(ell + (size_t)N_NODES * ELL_CAP);     // N ints
    int*   gbase  = cursor + N_NODES;                            // 256 ints (memset)
    unsigned int* part = (unsigned int*)(gbase + 256);           // 196*5120 uints

    const int* src = ei;
    const int* dst = ei + N_EDGES;

    hipMemsetAsync(gbase, 0, 256 * sizeof(int), stream);

    prep_kernel<<<NBP + NB_W + NB_IN, 256, 0, stream>>>(
        src, dst, gbase, part, Wl, Wr, BT, x, W_in, b_in, ln_g, ln_b, h, hnb, a8);
    ell_kernel<<<NBUCK, 256, 0, stream>>>(part, gbase, ell, cursor, a8);

    for (int i = 0; i < N_LAYERS; ++i) {
        gather_kernel<<<(N_NODES + 15) / 16, 256, 0, stream>>>(cursor, ell, a8);
        int mode = (i + 1 < N_LAYERS) ? 1 : 2;
        const float* g_next = ln_g + (mode == 1 ? (size_t)(i + 1) * HID : 0);
        const float* b_next = ln_b + (mode == 1 ? (size_t)(i + 1) * HID : 0);
        conv_mfma_kernel<<<(N_NODES + 127) / 128, 256, 0, stream>>>(
            h, a8, a8, hnb, BT + (size_t)i * 128 * 256, bl + i * HID,
            g_next, b_next, h, W_out, b_out, out, mode);
    }
}